// Round 8
// baseline (155.582 us; speedup 1.0000x reference)
//
#include <hip/hip_runtime.h>
#include <stdint.h>

// CapsuleLayer dynamic routing, fused. Round 8:
//  - identical to round 7 EXCEPT __launch_bounds__(512, 2): the (512,4)
//    bound made the backend chase 8 waves/SIMD (VGPR=64) and spill 54 MB
//    of scratch. (512,2) empirically targets ~128 regs: <=128 keeps the
//    LDS-limited 2 blocks/CU, and BT=2 demand (~100) fits without spill.
//  - BT=2 -> LDS 75 KB -> 2 blocks/CU -> 16 waves/CU; grid 1280 = 5*256
//  - priors in LDS (bf16 pairs); XCD-grouped c-major swizzle
//
// x:  [B=256, N=1152, CIN=8] fp32 | W: [10, 1152, 8, 16] fp32
// out:[10, B, 1, 1, 16] fp32

constexpr int NCAPS  = 10;
constexpr int BATCH  = 256;
constexpr int NROUTE = 1152;
constexpr int CIN    = 8;
constexpr int COUT   = 16;
constexpr int T      = 512;                      // 8 waves
constexpr int NWAVES = T / 64;
constexpr int BT     = 2;                        // batches per block
constexpr int NSTEP  = NROUTE / (NWAVES * 16);   // 9
constexpr int BG     = BATCH / BT;               // 128
constexpr int GRID   = NCAPS * BG;               // 1280 (=8*160, bijective swizzle)
constexpr int CPX    = GRID / 8;                 // 160 blocks per XCD

// Priors in LDS: plane g=0 holds o={4oq,4oq+1} packed, g=1 holds {4oq+2,4oq+3}.
// u32 index ((g*BT+b)*NROUTE + n)*4 + oq -> per-wave bank = lane%32 (2-way, free).
struct SMem {
    uint32_t pk[2][BT][NROUTE][4];   // 73728 B
    float red16[NWAVES][BT][COUT];   // 1024 B
    float sred[NWAVES][BT];          // 64 B
};
static_assert(sizeof(SMem) <= 78 * 1024, "LDS too big for 2 blocks/CU");

__device__ inline uint32_t bf16rne(float f) {
    uint32_t u = __float_as_uint(f);
    return (u + 0x7fffu + ((u >> 16) & 1u)) >> 16;
}
__device__ inline uint32_t packbf(float a, float b) {
    return (bf16rne(a) << 16) | bf16rne(b);
}
__device__ inline float2 unpk(uint32_t u) {
    return make_float2(__uint_as_float(u & 0xffff0000u),
                       __uint_as_float(u << 16));
}
__device__ inline float fcomp(const float4& v, int j) {   // j compile-time
    return j == 0 ? v.x : j == 1 ? v.y : j == 2 ? v.z : v.w;
}

#define LOADW(KK, BUF) do {                                                      \
    const int n_ = (KK) * 128 + nbase;                                           \
    const float4* wp_ = reinterpret_cast<const float4*>(Wc + (size_t)n_ * 128) + oq; \
    _Pragma("unroll")                                                            \
    for (int i_ = 0; i_ < 8; ++i_) wreg[BUF][i_] = wp_[i_ * 4];                  \
} while (0)

#define LOADX(KK, BUF) do {                                                      \
    const int n_ = (KK) * 128 + nbase;                                           \
    _Pragma("unroll")                                                            \
    for (int b_ = 0; b_ < BT; ++b_) {                                            \
        const float4* xp_ = reinterpret_cast<const float4*>(                     \
            xbase + (size_t)b_ * (NROUTE * CIN) + (size_t)n_ * CIN);             \
        xreg[BUF][b_ * 2 + 0] = xp_[0];                                          \
        xreg[BUF][b_ * 2 + 1] = xp_[1];                                          \
    }                                                                            \
} while (0)

__global__ __launch_bounds__(T, 2)
void capsule_routing_kernel(const float* __restrict__ x,
                            const float* __restrict__ Wt,
                            float* __restrict__ out) {
    __shared__ SMem sm;
    const int phys    = blockIdx.x;
    const int logical = (phys & 7) * CPX + (phys >> 3);   // XCD-grouped, c-major
    const int c  = logical / BG;
    const int b0 = (logical % BG) * BT;
    const int tid  = threadIdx.x;
    const int lane = tid & 63;
    const int wid  = tid >> 6;
    const int nn   = lane >> 2;
    const int oq   = lane & 3;
    const int nbase = wid * 16 + nn;

    const float* Wc    = Wt + (size_t)c * NROUTE * (CIN * COUT);
    const float* xbase = x + (size_t)b0 * NROUTE * CIN;

    float part[BT][4], s[BT][4], v[BT][4];

    // ---- prior phase: 2-deep register pipeline, store bf16 pairs to LDS,
    //      accumulate the iter-0 (uniform-probs) sums in fp32 on the fly ---
    {
        float4 wreg[2][8];
        float4 xreg[2][BT * 2];
#pragma unroll
        for (int b = 0; b < BT; ++b)
#pragma unroll
            for (int j = 0; j < 4; ++j) part[b][j] = 0.f;

        LOADW(0, 0);
        LOADX(0, 0);
#pragma unroll
        for (int k = 0; k < NSTEP; ++k) {
            const int cur = k & 1;
            if (k + 1 < NSTEP) {
                if (cur == 0) { LOADW(k + 1, 1); LOADX(k + 1, 1); }
                else          { LOADW(k + 1, 0); LOADX(k + 1, 0); }
            }
            const int n = k * 128 + nbase;
#pragma unroll
            for (int b = 0; b < BT; ++b) {
                float a0 = 0.f, a1 = 0.f, a2 = 0.f, a3 = 0.f;
#pragma unroll
                for (int i = 0; i < 8; ++i) {
                    float4 w4 = wreg[cur][i];
                    float xi = fcomp(xreg[cur][b * 2 + (i >> 2)], i & 3);
                    a0 = fmaf(xi, w4.x, a0);
                    a1 = fmaf(xi, w4.y, a1);
                    a2 = fmaf(xi, w4.z, a2);
                    a3 = fmaf(xi, w4.w, a3);
                }
                part[b][0] += a0; part[b][1] += a1;
                part[b][2] += a2; part[b][3] += a3;
                sm.pk[0][b][n][oq] = packbf(a0, a1);
                sm.pk[1][b][n][oq] = packbf(a2, a3);
            }
        }
    }

    float bl[BT][NSTEP];

    // ---- iteration 0: probs uniform 1/N ----------------------------------
#pragma unroll
    for (int b = 0; b < BT; ++b)
#pragma unroll
        for (int j = 0; j < 4; ++j) {
            float t = part[b][j];
#pragma unroll
            for (int off = 4; off < 64; off <<= 1) t += __shfl_xor(t, off, 64);
            part[b][j] = t;
        }
    __syncthreads();
    if (lane < 4) {
#pragma unroll
        for (int b = 0; b < BT; ++b)
#pragma unroll
            for (int j = 0; j < 4; ++j) sm.red16[wid][b][lane * 4 + j] = part[b][j];
    }
    __syncthreads();
#pragma unroll
    for (int b = 0; b < BT; ++b) {
        float sn = 0.f;
#pragma unroll
        for (int j = 0; j < 4; ++j) {
            float acc = sm.red16[0][b][oq * 4 + j];
#pragma unroll
            for (int w = 1; w < NWAVES; ++w) acc += sm.red16[w][b][oq * 4 + j];
            s[b][j] = acc * (1.0f / NROUTE);
            sn += s[b][j] * s[b][j];
        }
        sn += __shfl_xor(sn, 1, 64);
        sn += __shfl_xor(sn, 2, 64);
        float scale = sn / ((1.f + sn) * sqrtf(sn));
#pragma unroll
        for (int j = 0; j < 4; ++j) v[b][j] = s[b][j] * scale;
    }
    // logits after iter 0 (priors re-read from LDS, own slice, no barrier)
#pragma unroll
    for (int b = 0; b < BT; ++b)
#pragma unroll
        for (int k = 0; k < NSTEP; ++k) {
            const int n = k * 128 + nbase;
            float2 u0 = unpk(sm.pk[0][b][n][oq]);
            float2 u1 = unpk(sm.pk[1][b][n][oq]);
            float d = u0.x * v[b][0] + u0.y * v[b][1] + u1.x * v[b][2] + u1.y * v[b][3];
            d += __shfl_xor(d, 1, 64);
            d += __shfl_xor(d, 2, 64);
            bl[b][k] = d;
        }

    // ---- iterations 1, 2 --------------------------------------------------
#pragma unroll
    for (int it = 1; it < 3; ++it) {
        // softmax max over n; bl identical across quad -> offs 4..32 suffice
        float m[BT];
#pragma unroll
        for (int b = 0; b < BT; ++b) {
            float mm = bl[b][0];
#pragma unroll
            for (int k = 1; k < NSTEP; ++k) mm = fmaxf(mm, bl[b][k]);
#pragma unroll
            for (int off = 4; off < 64; off <<= 1) mm = fmaxf(mm, __shfl_xor(mm, off, 64));
            m[b] = mm;
        }
        __syncthreads();
        if (lane == 0) {
#pragma unroll
            for (int b = 0; b < BT; ++b) sm.sred[wid][b] = m[b];
        }
        __syncthreads();
#pragma unroll
        for (int b = 0; b < BT; ++b) {
            float mm = sm.sred[0][b];
#pragma unroll
            for (int w = 1; w < NWAVES; ++w) mm = fmaxf(mm, sm.sred[w][b]);
            m[b] = mm;
        }

        // fused pass: e = exp(bl-m) accumulated into Z and the 4 o-partials
        float es[BT];
#pragma unroll
        for (int b = 0; b < BT; ++b) {
            float ez = 0.f, a0 = 0, a1 = 0, a2 = 0, a3 = 0;
#pragma unroll
            for (int k = 0; k < NSTEP; ++k) {
                const int n = k * 128 + nbase;
                float ek = __expf(bl[b][k] - m[b]);
                ez += ek;
                float2 u0 = unpk(sm.pk[0][b][n][oq]);
                float2 u1 = unpk(sm.pk[1][b][n][oq]);
                a0 = fmaf(ek, u0.x, a0); a1 = fmaf(ek, u0.y, a1);
                a2 = fmaf(ek, u1.x, a2); a3 = fmaf(ek, u1.y, a3);
            }
#pragma unroll
            for (int off = 4; off < 64; off <<= 1) {
                a0 += __shfl_xor(a0, off, 64);
                a1 += __shfl_xor(a1, off, 64);
                a2 += __shfl_xor(a2, off, 64);
                a3 += __shfl_xor(a3, off, 64);
            }
            part[b][0] = a0; part[b][1] = a1; part[b][2] = a2; part[b][3] = a3;
            // ez identical across quad lanes -> offs 4..32 give wave total
#pragma unroll
            for (int off = 4; off < 64; off <<= 1) ez += __shfl_xor(ez, off, 64);
            es[b] = ez;
        }
        __syncthreads();
        if (lane < 4) {
#pragma unroll
            for (int b = 0; b < BT; ++b) {
#pragma unroll
                for (int j = 0; j < 4; ++j) sm.red16[wid][b][lane * 4 + j] = part[b][j];
                if (lane == 0) sm.sred[wid][b] = es[b];
            }
        }
        __syncthreads();
#pragma unroll
        for (int b = 0; b < BT; ++b) {
            float z = sm.sred[0][b];
#pragma unroll
            for (int w = 1; w < NWAVES; ++w) z += sm.sred[w][b];
            float invZ = 1.0f / z;
            float sn = 0.f;
#pragma unroll
            for (int j = 0; j < 4; ++j) {
                float acc = sm.red16[0][b][oq * 4 + j];
#pragma unroll
                for (int w = 1; w < NWAVES; ++w) acc += sm.red16[w][b][oq * 4 + j];
                s[b][j] = acc * invZ;
                sn += s[b][j] * s[b][j];
            }
            sn += __shfl_xor(sn, 1, 64);
            sn += __shfl_xor(sn, 2, 64);
            float scale = sn / ((1.f + sn) * sqrtf(sn));
#pragma unroll
            for (int j = 0; j < 4; ++j) v[b][j] = s[b][j] * scale;
        }

        if (it < 2) {
#pragma unroll
            for (int b = 0; b < BT; ++b)
#pragma unroll
                for (int k = 0; k < NSTEP; ++k) {
                    const int n = k * 128 + nbase;
                    float2 u0 = unpk(sm.pk[0][b][n][oq]);
                    float2 u1 = unpk(sm.pk[1][b][n][oq]);
                    float d = u0.x * v[b][0] + u0.y * v[b][1] + u1.x * v[b][2] + u1.y * v[b][3];
                    d += __shfl_xor(d, 1, 64);
                    d += __shfl_xor(d, 2, 64);
                    bl[b][k] += d;
                }
        }
    }

    // ---- write out[c, b0..b0+1, 0, 0, :] ---------------------------------
    if (tid < 4) {                         // wave 0, nn=0, lane==oq==tid
#pragma unroll
        for (int b = 0; b < BT; ++b) {
            float4 o = make_float4(v[b][0], v[b][1], v[b][2], v[b][3]);
            *reinterpret_cast<float4*>(
                out + ((size_t)(c * BATCH + b0 + b) * COUT) + tid * 4) = o;
        }
    }
}

extern "C" void kernel_launch(void* const* d_in, const int* in_sizes, int n_in,
                              void* d_out, int out_size, void* d_ws, size_t ws_size,
                              hipStream_t stream) {
    const float* x  = (const float*)d_in[0];
    const float* Wt = (const float*)d_in[1];
    float* out = (float*)d_out;
    capsule_routing_kernel<<<dim3(GRID), dim3(T), 0, stream>>>(x, Wt, out);
}

// Round 9
// 140.695 us; speedup vs baseline: 1.1058x; 1.1058x over previous
//
#include <hip/hip_runtime.h>
#include <stdint.h>

// CapsuleLayer dynamic routing. Round 9: TWO-KERNEL SPLIT via d_ws.
//  K1: priors GEMM -> ws (bf16). W fragment in regs, reused across all 256 b
//      -> W traffic 754 MB -> ~6 MB. No barriers, pure streaming.
//  K2: routing. One block per (c,b), T=192; priors loaded ONCE to registers
//      (lane owns full 16-o rows -> in-lane dots, butterfly reductions,
//      3-wave barriers only).
//  Fallback: round-8 fused kernel if ws_size < 94.4 MB.
//
// x:  [B=256, N=1152, CIN=8] fp32 | W: [10, 1152, 8, 16] fp32
// out:[10, B, 1, 1, 16] fp32
// ws layout: bf16 priors, u32 pair j of (c,b,n) = (o=2j hi, o=2j+1 lo)

constexpr int NCAPS  = 10;
constexpr int BATCH  = 256;
constexpr int NROUTE = 1152;
constexpr int CIN    = 8;
constexpr int COUT   = 16;
constexpr size_t WS_NEEDED = (size_t)NCAPS * BATCH * NROUTE * COUT * 2;  // 94.4 MB

__device__ inline uint32_t bf16rne(float f) {
    uint32_t u = __float_as_uint(f);
    return (u + 0x7fffu + ((u >> 16) & 1u)) >> 16;
}
__device__ inline uint32_t packbf(float a, float b) {
    return (bf16rne(a) << 16) | bf16rne(b);
}
__device__ inline float2 unpk(uint32_t u) {
    return make_float2(__uint_as_float(u & 0xffff0000u),
                       __uint_as_float(u << 16));
}
__device__ inline float fcomp(const float4& v, int j) {   // j compile-time
    return j == 0 ? v.x : j == 1 ? v.y : j == 2 ? v.z : v.w;
}

// ======================= K1: priors ====================================
// grid 720 = 10 c * 72 chunks (16 n each), swizzled chunk-major per XCD.
// T=256 (4 waves); wave w handles b in [w*64, w*64+64).
// lane: nn=lane>>2 (n in chunk), oq=lane&3 (o quad). W frag: 8 float4 regs.

#define K1LOADX(G, BUF)                                                      \
    {                                                                        \
        _Pragma("unroll") for (int bo = 0; bo < 2; ++bo) {                   \
            const int b_ = b0 + (G) * 2 + bo;                                \
            const float4* xp =                                               \
                reinterpret_cast<const float4*>(x) + ((size_t)b_ * NROUTE + n) * 2; \
            xbuf[BUF][bo][0] = xp[0];                                        \
            xbuf[BUF][bo][1] = xp[1];                                        \
        }                                                                    \
    }

__global__ __launch_bounds__(256)
void k1_priors(const float* __restrict__ x, const float* __restrict__ Wt,
               uint2* __restrict__ ws) {
    const int phys    = blockIdx.x;
    const int logical = (phys & 7) * 90 + (phys >> 3);    // 720 = 8*90 bijective
    const int c  = logical % 10;
    const int nc = logical / 10;                          // 0..71
    const int tid  = threadIdx.x;
    const int lane = tid & 63;
    const int wid  = tid >> 6;
    const int nn   = lane >> 2;
    const int oq   = lane & 3;
    const int n    = nc * 16 + nn;
    const int b0   = wid * 64;

    const float* Wc = Wt + (size_t)c * NROUTE * (CIN * COUT);
    const float4* wp =
        reinterpret_cast<const float4*>(Wc + (size_t)n * (CIN * COUT)) + oq;
    float4 wreg[8];
#pragma unroll
    for (int i = 0; i < 8; ++i) wreg[i] = wp[i * 4];

    const size_t wsbase = ((size_t)c * BATCH) * NROUTE * 4;  // uint2 units

    float4 xbuf[2][2][2];   // [buf][b-in-group][half]
    K1LOADX(0, 0)
#pragma unroll
    for (int g = 0; g < 32; ++g) {
        const int cur = g & 1;
        if (g < 31) {
            if (cur == 0) { K1LOADX(g + 1, 1) } else { K1LOADX(g + 1, 0) }
        }
#pragma unroll
        for (int bo = 0; bo < 2; ++bo) {
            const int b_ = b0 + g * 2 + bo;
            float a0 = 0.f, a1 = 0.f, a2 = 0.f, a3 = 0.f;
#pragma unroll
            for (int i = 0; i < 8; ++i) {
                float xi = fcomp(xbuf[cur][bo][i >> 2], i & 3);
                float4 w4 = wreg[i];
                a0 = fmaf(xi, w4.x, a0);
                a1 = fmaf(xi, w4.y, a1);
                a2 = fmaf(xi, w4.z, a2);
                a3 = fmaf(xi, w4.w, a3);
            }
            ws[wsbase + ((size_t)b_ * NROUTE + n) * 4 + oq] =
                make_uint2(packbf(a0, a1), packbf(a2, a3));
        }
    }
}

// ======================= K2: routing ===================================
// grid 2560 = 10*256; block = (c,b); T=192 (3 waves); thread owns 6 n's
// (n = tid + 192k), full 16 o per n in registers (pa/pb: 48 VGPRs).

#define UNPK_K(K, q)                                                          \
    {                                                                         \
        float2 t0 = unpk(pa[K].x), t1 = unpk(pa[K].y);                        \
        float2 t2 = unpk(pa[K].z), t3 = unpk(pa[K].w);                        \
        float2 t4 = unpk(pb[K].x), t5 = unpk(pb[K].y);                        \
        float2 t6 = unpk(pb[K].z), t7 = unpk(pb[K].w);                        \
        q[0] = t0.x; q[1] = t0.y; q[2]  = t1.x; q[3]  = t1.y;                 \
        q[4] = t2.x; q[5] = t2.y; q[6]  = t3.x; q[7]  = t3.y;                 \
        q[8] = t4.x; q[9] = t4.y; q[10] = t5.x; q[11] = t5.y;                 \
        q[12] = t6.x; q[13] = t6.y; q[14] = t7.x; q[15] = t7.y;               \
    }

__global__ __launch_bounds__(192)
void k2_route(const uint4* __restrict__ P4, float* __restrict__ out) {
    const int blk = blockIdx.x;
    const int c = blk >> 8;
    const int b = blk & 255;
    const int tid = threadIdx.x;
    const int lane = tid & 63;
    const int wid = tid >> 6;

    __shared__ float redv[3][16];
    __shared__ float redz[3];

    const uint4* Pb = P4 + (size_t)(c * BATCH + b) * NROUTE * 2;
    uint4 pa[6], pb[6];
#pragma unroll
    for (int k = 0; k < 6; ++k) {
        const size_t o = ((size_t)(tid + 192 * k)) * 2;
        pa[k] = Pb[o];
        pb[k] = Pb[o + 1];
    }

    float q[16], v[16], s[16];

    // ---- iter 0: uniform probs -------------------------------------------
    float part[16];
#pragma unroll
    for (int j = 0; j < 16; ++j) part[j] = 0.f;
#pragma unroll
    for (int k = 0; k < 6; ++k) {
        UNPK_K(k, q)
#pragma unroll
        for (int j = 0; j < 16; ++j) part[j] += q[j];
    }
#pragma unroll
    for (int j = 0; j < 16; ++j) {
#pragma unroll
        for (int off = 1; off < 64; off <<= 1) part[j] += __shfl_xor(part[j], off, 64);
    }
    __syncthreads();
    if (lane == 0) {
#pragma unroll
        for (int j = 0; j < 16; ++j) redv[wid][j] = part[j];
    }
    __syncthreads();
    {
        float sn = 0.f;
#pragma unroll
        for (int j = 0; j < 16; ++j) {
            s[j] = (redv[0][j] + redv[1][j] + redv[2][j]) * (1.0f / NROUTE);
            sn += s[j] * s[j];
        }
        float scale = sn / ((1.f + sn) * sqrtf(sn));
#pragma unroll
        for (int j = 0; j < 16; ++j) v[j] = s[j] * scale;
    }
    float bl[6];
#pragma unroll
    for (int k = 0; k < 6; ++k) {
        UNPK_K(k, q)
        float d = 0.f;
#pragma unroll
        for (int j = 0; j < 16; ++j) d = fmaf(q[j], v[j], d);
        bl[k] = d;
    }

    // ---- iters 1, 2 -------------------------------------------------------
#pragma unroll
    for (int it = 1; it < 3; ++it) {
        float mm = bl[0];
#pragma unroll
        for (int k = 1; k < 6; ++k) mm = fmaxf(mm, bl[k]);
#pragma unroll
        for (int off = 1; off < 64; off <<= 1) mm = fmaxf(mm, __shfl_xor(mm, off, 64));
        __syncthreads();
        if (lane == 0) redz[wid] = mm;
        __syncthreads();
        mm = fmaxf(fmaxf(redz[0], redz[1]), redz[2]);

        float ez = 0.f, acc[16], e[6];
#pragma unroll
        for (int j = 0; j < 16; ++j) acc[j] = 0.f;
#pragma unroll
        for (int k = 0; k < 6; ++k) {
            e[k] = __expf(bl[k] - mm);
            ez += e[k];
            UNPK_K(k, q)
#pragma unroll
            for (int j = 0; j < 16; ++j) acc[j] = fmaf(e[k], q[j], acc[j]);
        }
#pragma unroll
        for (int off = 1; off < 64; off <<= 1) ez += __shfl_xor(ez, off, 64);
#pragma unroll
        for (int j = 0; j < 16; ++j) {
#pragma unroll
            for (int off = 1; off < 64; off <<= 1) acc[j] += __shfl_xor(acc[j], off, 64);
        }
        __syncthreads();
        if (lane == 0) {
            redz[wid] = ez;
#pragma unroll
            for (int j = 0; j < 16; ++j) redv[wid][j] = acc[j];
        }
        __syncthreads();
        const float invZ = 1.0f / (redz[0] + redz[1] + redz[2]);
        float sn = 0.f;
#pragma unroll
        for (int j = 0; j < 16; ++j) {
            s[j] = (redv[0][j] + redv[1][j] + redv[2][j]) * invZ;
            sn += s[j] * s[j];
        }
        float scale = sn / ((1.f + sn) * sqrtf(sn));
#pragma unroll
        for (int j = 0; j < 16; ++j) v[j] = s[j] * scale;

        if (it < 2) {
#pragma unroll
            for (int k = 0; k < 6; ++k) {
                UNPK_K(k, q)
                float d = 0.f;
#pragma unroll
                for (int j = 0; j < 16; ++j) d = fmaf(q[j], v[j], d);
                bl[k] += d;
            }
        }
    }

    if (tid == 0) {
        float* ob = out + (size_t)(c * BATCH + b) * COUT;
        *reinterpret_cast<float4*>(ob + 0)  = make_float4(v[0], v[1], v[2], v[3]);
        *reinterpret_cast<float4*>(ob + 4)  = make_float4(v[4], v[5], v[6], v[7]);
        *reinterpret_cast<float4*>(ob + 8)  = make_float4(v[8], v[9], v[10], v[11]);
        *reinterpret_cast<float4*>(ob + 12) = make_float4(v[12], v[13], v[14], v[15]);
    }
}

// ======================= fallback: round-8 fused kernel =================
constexpr int T      = 512;
constexpr int NWAVES = T / 64;
constexpr int BT     = 2;
constexpr int NSTEP  = NROUTE / (NWAVES * 16);   // 9
constexpr int BG     = BATCH / BT;               // 128
constexpr int FGRID  = NCAPS * BG;               // 1280
constexpr int CPX    = FGRID / 8;                // 160

struct SMem {
    uint32_t pk[2][BT][NROUTE][4];
    float red16[NWAVES][BT][COUT];
    float sred[NWAVES][BT];
};

#define LOADW(KK, BUF) do {                                                      \
    const int n_ = (KK) * 128 + nbase;                                           \
    const float4* wp_ = reinterpret_cast<const float4*>(Wc + (size_t)n_ * 128) + oq; \
    _Pragma("unroll")                                                            \
    for (int i_ = 0; i_ < 8; ++i_) wreg[BUF][i_] = wp_[i_ * 4];                  \
} while (0)

#define LOADX(KK, BUF) do {                                                      \
    const int n_ = (KK) * 128 + nbase;                                           \
    _Pragma("unroll")                                                            \
    for (int b_ = 0; b_ < BT; ++b_) {                                            \
        const float4* xp_ = reinterpret_cast<const float4*>(                     \
            xbase + (size_t)b_ * (NROUTE * CIN) + (size_t)n_ * CIN);             \
        xreg[BUF][b_ * 2 + 0] = xp_[0];                                          \
        xreg[BUF][b_ * 2 + 1] = xp_[1];                                          \
    }                                                                            \
} while (0)

__global__ __launch_bounds__(T, 2)
void capsule_routing_kernel(const float* __restrict__ x,
                            const float* __restrict__ Wt,
                            float* __restrict__ out) {
    __shared__ SMem sm;
    const int phys    = blockIdx.x;
    const int logical = (phys & 7) * CPX + (phys >> 3);
    const int c  = logical / BG;
    const int b0 = (logical % BG) * BT;
    const int tid  = threadIdx.x;
    const int lane = tid & 63;
    const int wid  = tid >> 6;
    const int nn   = lane >> 2;
    const int oq   = lane & 3;
    const int nbase = wid * 16 + nn;

    const float* Wc    = Wt + (size_t)c * NROUTE * (CIN * COUT);
    const float* xbase = x + (size_t)b0 * NROUTE * CIN;

    float part[BT][4], s[BT][4], v[BT][4];
    {
        float4 wreg[2][8];
        float4 xreg[2][BT * 2];
#pragma unroll
        for (int b = 0; b < BT; ++b)
#pragma unroll
            for (int j = 0; j < 4; ++j) part[b][j] = 0.f;
        LOADW(0, 0);
        LOADX(0, 0);
#pragma unroll
        for (int k = 0; k < NSTEP; ++k) {
            const int cur = k & 1;
            if (k + 1 < NSTEP) {
                if (cur == 0) { LOADW(k + 1, 1); LOADX(k + 1, 1); }
                else          { LOADW(k + 1, 0); LOADX(k + 1, 0); }
            }
            const int n = k * 128 + nbase;
#pragma unroll
            for (int b = 0; b < BT; ++b) {
                float a0 = 0.f, a1 = 0.f, a2 = 0.f, a3 = 0.f;
#pragma unroll
                for (int i = 0; i < 8; ++i) {
                    float4 w4 = wreg[cur][i];
                    float xi = fcomp(xreg[cur][b * 2 + (i >> 2)], i & 3);
                    a0 = fmaf(xi, w4.x, a0);
                    a1 = fmaf(xi, w4.y, a1);
                    a2 = fmaf(xi, w4.z, a2);
                    a3 = fmaf(xi, w4.w, a3);
                }
                part[b][0] += a0; part[b][1] += a1;
                part[b][2] += a2; part[b][3] += a3;
                sm.pk[0][b][n][oq] = packbf(a0, a1);
                sm.pk[1][b][n][oq] = packbf(a2, a3);
            }
        }
    }
    float bl[BT][NSTEP];
#pragma unroll
    for (int b = 0; b < BT; ++b)
#pragma unroll
        for (int j = 0; j < 4; ++j) {
            float t = part[b][j];
#pragma unroll
            for (int off = 4; off < 64; off <<= 1) t += __shfl_xor(t, off, 64);
            part[b][j] = t;
        }
    __syncthreads();
    if (lane < 4) {
#pragma unroll
        for (int b = 0; b < BT; ++b)
#pragma unroll
            for (int j = 0; j < 4; ++j) sm.red16[wid][b][lane * 4 + j] = part[b][j];
    }
    __syncthreads();
#pragma unroll
    for (int b = 0; b < BT; ++b) {
        float sn = 0.f;
#pragma unroll
        for (int j = 0; j < 4; ++j) {
            float acc = sm.red16[0][b][oq * 4 + j];
#pragma unroll
            for (int w = 1; w < NWAVES; ++w) acc += sm.red16[w][b][oq * 4 + j];
            s[b][j] = acc * (1.0f / NROUTE);
            sn += s[b][j] * s[b][j];
        }
        sn += __shfl_xor(sn, 1, 64);
        sn += __shfl_xor(sn, 2, 64);
        float scale = sn / ((1.f + sn) * sqrtf(sn));
#pragma unroll
        for (int j = 0; j < 4; ++j) v[b][j] = s[b][j] * scale;
    }
#pragma unroll
    for (int b = 0; b < BT; ++b)
#pragma unroll
        for (int k = 0; k < NSTEP; ++k) {
            const int n = k * 128 + nbase;
            float2 u0 = unpk(sm.pk[0][b][n][oq]);
            float2 u1 = unpk(sm.pk[1][b][n][oq]);
            float d = u0.x * v[b][0] + u0.y * v[b][1] + u1.x * v[b][2] + u1.y * v[b][3];
            d += __shfl_xor(d, 1, 64);
            d += __shfl_xor(d, 2, 64);
            bl[b][k] = d;
        }
#pragma unroll
    for (int it = 1; it < 3; ++it) {
        float m[BT];
#pragma unroll
        for (int b = 0; b < BT; ++b) {
            float mm = bl[b][0];
#pragma unroll
            for (int k = 1; k < NSTEP; ++k) mm = fmaxf(mm, bl[b][k]);
#pragma unroll
            for (int off = 4; off < 64; off <<= 1) mm = fmaxf(mm, __shfl_xor(mm, off, 64));
            m[b] = mm;
        }
        __syncthreads();
        if (lane == 0) {
#pragma unroll
            for (int b = 0; b < BT; ++b) sm.sred[wid][b] = m[b];
        }
        __syncthreads();
#pragma unroll
        for (int b = 0; b < BT; ++b) {
            float mm = sm.sred[0][b];
#pragma unroll
            for (int w = 1; w < NWAVES; ++w) mm = fmaxf(mm, sm.sred[w][b]);
            m[b] = mm;
        }
        float es[BT];
#pragma unroll
        for (int b = 0; b < BT; ++b) {
            float ez = 0.f, a0 = 0, a1 = 0, a2 = 0, a3 = 0;
#pragma unroll
            for (int k = 0; k < NSTEP; ++k) {
                const int n = k * 128 + nbase;
                float ek = __expf(bl[b][k] - m[b]);
                ez += ek;
                float2 u0 = unpk(sm.pk[0][b][n][oq]);
                float2 u1 = unpk(sm.pk[1][b][n][oq]);
                a0 = fmaf(ek, u0.x, a0); a1 = fmaf(ek, u0.y, a1);
                a2 = fmaf(ek, u1.x, a2); a3 = fmaf(ek, u1.y, a3);
            }
#pragma unroll
            for (int off = 4; off < 64; off <<= 1) {
                a0 += __shfl_xor(a0, off, 64);
                a1 += __shfl_xor(a1, off, 64);
                a2 += __shfl_xor(a2, off, 64);
                a3 += __shfl_xor(a3, off, 64);
            }
            part[b][0] = a0; part[b][1] = a1; part[b][2] = a2; part[b][3] = a3;
#pragma unroll
            for (int off = 4; off < 64; off <<= 1) ez += __shfl_xor(ez, off, 64);
            es[b] = ez;
        }
        __syncthreads();
        if (lane < 4) {
#pragma unroll
            for (int b = 0; b < BT; ++b) {
#pragma unroll
                for (int j = 0; j < 4; ++j) sm.red16[wid][b][lane * 4 + j] = part[b][j];
                if (lane == 0) sm.sred[wid][b] = es[b];
            }
        }
        __syncthreads();
#pragma unroll
        for (int b = 0; b < BT; ++b) {
            float z = sm.sred[0][b];
#pragma unroll
            for (int w = 1; w < NWAVES; ++w) z += sm.sred[w][b];
            float invZ = 1.0f / z;
            float sn = 0.f;
#pragma unroll
            for (int j = 0; j < 4; ++j) {
                float acc = sm.red16[0][b][oq * 4 + j];
#pragma unroll
                for (int w = 1; w < NWAVES; ++w) acc += sm.red16[w][b][oq * 4 + j];
                s[b][j] = acc * invZ;
                sn += s[b][j] * s[b][j];
            }
            sn += __shfl_xor(sn, 1, 64);
            sn += __shfl_xor(sn, 2, 64);
            float scale = sn / ((1.f + sn) * sqrtf(sn));
#pragma unroll
            for (int j = 0; j < 4; ++j) v[b][j] = s[b][j] * scale;
        }
        if (it < 2) {
#pragma unroll
            for (int b = 0; b < BT; ++b)
#pragma unroll
                for (int k = 0; k < NSTEP; ++k) {
                    const int n = k * 128 + nbase;
                    float2 u0 = unpk(sm.pk[0][b][n][oq]);
                    float2 u1 = unpk(sm.pk[1][b][n][oq]);
                    float d = u0.x * v[b][0] + u0.y * v[b][1] + u1.x * v[b][2] + u1.y * v[b][3];
                    d += __shfl_xor(d, 1, 64);
                    d += __shfl_xor(d, 2, 64);
                    bl[b][k] += d;
                }
        }
    }
    if (tid < 4) {
#pragma unroll
        for (int b = 0; b < BT; ++b) {
            float4 o = make_float4(v[b][0], v[b][1], v[b][2], v[b][3]);
            *reinterpret_cast<float4*>(
                out + ((size_t)(c * BATCH + b0 + b) * COUT) + tid * 4) = o;
        }
    }
}

extern "C" void kernel_launch(void* const* d_in, const int* in_sizes, int n_in,
                              void* d_out, int out_size, void* d_ws, size_t ws_size,
                              hipStream_t stream) {
    const float* x  = (const float*)d_in[0];
    const float* Wt = (const float*)d_in[1];
    float* out = (float*)d_out;
    if (ws_size >= WS_NEEDED) {
        k1_priors<<<dim3(720), dim3(256), 0, stream>>>(x, Wt, (uint2*)d_ws);
        k2_route<<<dim3(NCAPS * BATCH), dim3(192), 0, stream>>>(
            (const uint4*)d_ws, out);
    } else {
        capsule_routing_kernel<<<dim3(FGRID), dim3(T), 0, stream>>>(x, Wt, out);
    }
}

// Round 10
// 130.972 us; speedup vs baseline: 1.1879x; 1.0742x over previous
//
#include <hip/hip_runtime.h>
#include <stdint.h>

// CapsuleLayer dynamic routing. Round 10: two-kernel split, k1 rewritten.
//  K1 v2: lane owns (n, o-half) -> uint4 (16B) stores, 1KB/wave contiguous;
//         grid 1440, wave does 16 b -> 5760 waves (2x round 9). W frag (16
//         float4) loaded once per wave, reused over 16 b. Layout of ws is
//         IDENTICAL to round 9, so k2 is byte-for-byte unchanged.
//  K2: unchanged from round 9 (clean attribution of k1 delta).
//  Fallback: round-8 fused kernel if ws_size < 94.4 MB.
//
// x:  [B=256, N=1152, CIN=8] fp32 | W: [10, 1152, 8, 16] fp32
// out:[10, B, 1, 1, 16] fp32
// ws: bf16 priors [c][b][n][o], u32 pair j = (o=2j hi, o=2j+1 lo)

constexpr int NCAPS  = 10;
constexpr int BATCH  = 256;
constexpr int NROUTE = 1152;
constexpr int CIN    = 8;
constexpr int COUT   = 16;
constexpr size_t WS_NEEDED = (size_t)NCAPS * BATCH * NROUTE * COUT * 2;  // 94.4 MB

__device__ inline uint32_t bf16rne(float f) {
    uint32_t u = __float_as_uint(f);
    return (u + 0x7fffu + ((u >> 16) & 1u)) >> 16;
}
__device__ inline uint32_t packbf(float a, float b) {
    return (bf16rne(a) << 16) | bf16rne(b);
}
__device__ inline float2 unpk(uint32_t u) {
    return make_float2(__uint_as_float(u & 0xffff0000u),
                       __uint_as_float(u << 16));
}
__device__ inline float fcomp(const float4& v, int j) {   // j compile-time
    return j == 0 ? v.x : j == 1 ? v.y : j == 2 ? v.z : v.w;
}

// ======================= K1 v2: priors =================================
// grid 1440 = 10 c * 36 nchunks(32 n) * 4 bgroups, XCD-swizzled c-major.
// T=256 (4 waves); wave w handles b in [bg*64 + w*16, +16).
// lane: nn=lane>>1 (32 n per wave), oh=lane&1 (o-half: 8 outputs).
// W frag: 16 float4 regs (lane's n row, its half). Store: uint4 = 8 bf16.

#define K1X(J, BUF)                                                          \
    {                                                                        \
        const int b_ = b0 + (J);                                             \
        const float4* xp =                                                   \
            reinterpret_cast<const float4*>(x) + ((size_t)b_ * NROUTE + n) * 2; \
        xb[BUF][0] = xp[0];                                                  \
        xb[BUF][1] = xp[1];                                                  \
    }

__global__ __launch_bounds__(256, 2)
void k1_priors(const float* __restrict__ x, const float* __restrict__ Wt,
               uint4* __restrict__ ws) {
    const int phys    = blockIdx.x;
    const int logical = (phys & 7) * 180 + (phys >> 3);   // 1440 = 8*180 bijective
    const int c   = logical / 144;                        // 144 blocks per c
    const int rem = logical % 144;
    const int nc  = rem >> 2;                             // 0..35
    const int bg  = rem & 3;                              // 0..3
    const int tid  = threadIdx.x;
    const int lane = tid & 63;
    const int wid  = tid >> 6;
    const int nn   = lane >> 1;                           // 0..31
    const int oh   = lane & 1;                            // 0..1
    const int n    = nc * 32 + nn;
    const int b0   = bg * 64 + wid * 16;

    // W fragment: row n, half oh -> 8 floats per i, i=0..7 -> 16 float4
    const float4* wp =
        reinterpret_cast<const float4*>(Wt + ((size_t)c * NROUTE + n) * (CIN * COUT))
        + oh * 2;
    float4 wreg[16];
#pragma unroll
    for (int i = 0; i < 8; ++i) {
        wreg[2 * i]     = wp[i * 4];
        wreg[2 * i + 1] = wp[i * 4 + 1];
    }

    uint4* wsc = ws + (size_t)c * BATCH * NROUTE * 2;     // uint4 units

    float4 xb[2][2];
    K1X(0, 0)
#pragma unroll
    for (int j = 0; j < 16; ++j) {
        const int cur = j & 1;
        if (j < 15) {
            if (cur == 0) { K1X(j + 1, 1) } else { K1X(j + 1, 0) }
        }
        const int b = b0 + j;
        float a0 = 0.f, a1 = 0.f, a2 = 0.f, a3 = 0.f;
        float a4 = 0.f, a5 = 0.f, a6 = 0.f, a7 = 0.f;
#pragma unroll
        for (int i = 0; i < 8; ++i) {
            const float xi = fcomp(xb[cur][i >> 2], i & 3);
            const float4 w0 = wreg[2 * i];
            const float4 w1 = wreg[2 * i + 1];
            a0 = fmaf(xi, w0.x, a0); a1 = fmaf(xi, w0.y, a1);
            a2 = fmaf(xi, w0.z, a2); a3 = fmaf(xi, w0.w, a3);
            a4 = fmaf(xi, w1.x, a4); a5 = fmaf(xi, w1.y, a5);
            a6 = fmaf(xi, w1.z, a6); a7 = fmaf(xi, w1.w, a7);
        }
        wsc[((size_t)b * NROUTE + n) * 2 + oh] =
            make_uint4(packbf(a0, a1), packbf(a2, a3),
                       packbf(a4, a5), packbf(a6, a7));
    }
}

// ======================= K2: routing (unchanged from round 9) ==========
#define UNPK_K(K, q)                                                          \
    {                                                                         \
        float2 t0 = unpk(pa[K].x), t1 = unpk(pa[K].y);                        \
        float2 t2 = unpk(pa[K].z), t3 = unpk(pa[K].w);                        \
        float2 t4 = unpk(pb[K].x), t5 = unpk(pb[K].y);                        \
        float2 t6 = unpk(pb[K].z), t7 = unpk(pb[K].w);                        \
        q[0] = t0.x; q[1] = t0.y; q[2]  = t1.x; q[3]  = t1.y;                 \
        q[4] = t2.x; q[5] = t2.y; q[6]  = t3.x; q[7]  = t3.y;                 \
        q[8] = t4.x; q[9] = t4.y; q[10] = t5.x; q[11] = t5.y;                 \
        q[12] = t6.x; q[13] = t6.y; q[14] = t7.x; q[15] = t7.y;               \
    }

__global__ __launch_bounds__(192)
void k2_route(const uint4* __restrict__ P4, float* __restrict__ out) {
    const int blk = blockIdx.x;
    const int c = blk >> 8;
    const int b = blk & 255;
    const int tid = threadIdx.x;
    const int lane = tid & 63;
    const int wid = tid >> 6;

    __shared__ float redv[3][16];
    __shared__ float redz[3];

    const uint4* Pb = P4 + (size_t)(c * BATCH + b) * NROUTE * 2;
    uint4 pa[6], pb[6];
#pragma unroll
    for (int k = 0; k < 6; ++k) {
        const size_t o = ((size_t)(tid + 192 * k)) * 2;
        pa[k] = Pb[o];
        pb[k] = Pb[o + 1];
    }

    float q[16], v[16], s[16];

    float part[16];
#pragma unroll
    for (int j = 0; j < 16; ++j) part[j] = 0.f;
#pragma unroll
    for (int k = 0; k < 6; ++k) {
        UNPK_K(k, q)
#pragma unroll
        for (int j = 0; j < 16; ++j) part[j] += q[j];
    }
#pragma unroll
    for (int j = 0; j < 16; ++j) {
#pragma unroll
        for (int off = 1; off < 64; off <<= 1) part[j] += __shfl_xor(part[j], off, 64);
    }
    __syncthreads();
    if (lane == 0) {
#pragma unroll
        for (int j = 0; j < 16; ++j) redv[wid][j] = part[j];
    }
    __syncthreads();
    {
        float sn = 0.f;
#pragma unroll
        for (int j = 0; j < 16; ++j) {
            s[j] = (redv[0][j] + redv[1][j] + redv[2][j]) * (1.0f / NROUTE);
            sn += s[j] * s[j];
        }
        float scale = sn / ((1.f + sn) * sqrtf(sn));
#pragma unroll
        for (int j = 0; j < 16; ++j) v[j] = s[j] * scale;
    }
    float bl[6];
#pragma unroll
    for (int k = 0; k < 6; ++k) {
        UNPK_K(k, q)
        float d = 0.f;
#pragma unroll
        for (int j = 0; j < 16; ++j) d = fmaf(q[j], v[j], d);
        bl[k] = d;
    }

#pragma unroll
    for (int it = 1; it < 3; ++it) {
        float mm = bl[0];
#pragma unroll
        for (int k = 1; k < 6; ++k) mm = fmaxf(mm, bl[k]);
#pragma unroll
        for (int off = 1; off < 64; off <<= 1) mm = fmaxf(mm, __shfl_xor(mm, off, 64));
        __syncthreads();
        if (lane == 0) redz[wid] = mm;
        __syncthreads();
        mm = fmaxf(fmaxf(redz[0], redz[1]), redz[2]);

        float ez = 0.f, acc[16], e[6];
#pragma unroll
        for (int j = 0; j < 16; ++j) acc[j] = 0.f;
#pragma unroll
        for (int k = 0; k < 6; ++k) {
            e[k] = __expf(bl[k] - mm);
            ez += e[k];
            UNPK_K(k, q)
#pragma unroll
            for (int j = 0; j < 16; ++j) acc[j] = fmaf(e[k], q[j], acc[j]);
        }
#pragma unroll
        for (int off = 1; off < 64; off <<= 1) ez += __shfl_xor(ez, off, 64);
#pragma unroll
        for (int j = 0; j < 16; ++j) {
#pragma unroll
            for (int off = 1; off < 64; off <<= 1) acc[j] += __shfl_xor(acc[j], off, 64);
        }
        __syncthreads();
        if (lane == 0) {
            redz[wid] = ez;
#pragma unroll
            for (int j = 0; j < 16; ++j) redv[wid][j] = acc[j];
        }
        __syncthreads();
        const float invZ = 1.0f / (redz[0] + redz[1] + redz[2]);
        float sn = 0.f;
#pragma unroll
        for (int j = 0; j < 16; ++j) {
            s[j] = (redv[0][j] + redv[1][j] + redv[2][j]) * invZ;
            sn += s[j] * s[j];
        }
        float scale = sn / ((1.f + sn) * sqrtf(sn));
#pragma unroll
        for (int j = 0; j < 16; ++j) v[j] = s[j] * scale;

        if (it < 2) {
#pragma unroll
            for (int k = 0; k < 6; ++k) {
                UNPK_K(k, q)
                float d = 0.f;
#pragma unroll
                for (int j = 0; j < 16; ++j) d = fmaf(q[j], v[j], d);
                bl[k] += d;
            }
        }
    }

    if (tid == 0) {
        float* ob = out + (size_t)(c * BATCH + b) * COUT;
        *reinterpret_cast<float4*>(ob + 0)  = make_float4(v[0], v[1], v[2], v[3]);
        *reinterpret_cast<float4*>(ob + 4)  = make_float4(v[4], v[5], v[6], v[7]);
        *reinterpret_cast<float4*>(ob + 8)  = make_float4(v[8], v[9], v[10], v[11]);
        *reinterpret_cast<float4*>(ob + 12) = make_float4(v[12], v[13], v[14], v[15]);
    }
}

// ======================= fallback: round-8 fused kernel =================
constexpr int T      = 512;
constexpr int NWAVES = T / 64;
constexpr int BT     = 2;
constexpr int NSTEP  = NROUTE / (NWAVES * 16);   // 9
constexpr int BG     = BATCH / BT;               // 128
constexpr int FGRID  = NCAPS * BG;               // 1280
constexpr int CPX    = FGRID / 8;                // 160

struct SMem {
    uint32_t pk[2][BT][NROUTE][4];
    float red16[NWAVES][BT][COUT];
    float sred[NWAVES][BT];
};

#define LOADW(KK, BUF) do {                                                      \
    const int n_ = (KK) * 128 + nbase;                                           \
    const float4* wp_ = reinterpret_cast<const float4*>(Wc + (size_t)n_ * 128) + oq; \
    _Pragma("unroll")                                                            \
    for (int i_ = 0; i_ < 8; ++i_) wreg[BUF][i_] = wp_[i_ * 4];                  \
} while (0)

#define LOADX(KK, BUF) do {                                                      \
    const int n_ = (KK) * 128 + nbase;                                           \
    _Pragma("unroll")                                                            \
    for (int b_ = 0; b_ < BT; ++b_) {                                            \
        const float4* xp_ = reinterpret_cast<const float4*>(                     \
            xbase + (size_t)b_ * (NROUTE * CIN) + (size_t)n_ * CIN);             \
        xreg[BUF][b_ * 2 + 0] = xp_[0];                                          \
        xreg[BUF][b_ * 2 + 1] = xp_[1];                                          \
    }                                                                            \
} while (0)

__global__ __launch_bounds__(T, 2)
void capsule_routing_kernel(const float* __restrict__ x,
                            const float* __restrict__ Wt,
                            float* __restrict__ out) {
    __shared__ SMem sm;
    const int phys    = blockIdx.x;
    const int logical = (phys & 7) * CPX + (phys >> 3);
    const int c  = logical / BG;
    const int b0 = (logical % BG) * BT;
    const int tid  = threadIdx.x;
    const int lane = tid & 63;
    const int wid  = tid >> 6;
    const int nn   = lane >> 2;
    const int oq   = lane & 3;
    const int nbase = wid * 16 + nn;

    const float* Wc    = Wt + (size_t)c * NROUTE * (CIN * COUT);
    const float* xbase = x + (size_t)b0 * NROUTE * CIN;

    float part[BT][4], s[BT][4], v[BT][4];
    {
        float4 wreg[2][8];
        float4 xreg[2][BT * 2];
#pragma unroll
        for (int b = 0; b < BT; ++b)
#pragma unroll
            for (int j = 0; j < 4; ++j) part[b][j] = 0.f;
        LOADW(0, 0);
        LOADX(0, 0);
#pragma unroll
        for (int k = 0; k < NSTEP; ++k) {
            const int cur = k & 1;
            if (k + 1 < NSTEP) {
                if (cur == 0) { LOADW(k + 1, 1); LOADX(k + 1, 1); }
                else          { LOADW(k + 1, 0); LOADX(k + 1, 0); }
            }
            const int n = k * 128 + nbase;
#pragma unroll
            for (int b = 0; b < BT; ++b) {
                float a0 = 0.f, a1 = 0.f, a2 = 0.f, a3 = 0.f;
#pragma unroll
                for (int i = 0; i < 8; ++i) {
                    float4 w4 = wreg[cur][i];
                    float xi = fcomp(xreg[cur][b * 2 + (i >> 2)], i & 3);
                    a0 = fmaf(xi, w4.x, a0);
                    a1 = fmaf(xi, w4.y, a1);
                    a2 = fmaf(xi, w4.z, a2);
                    a3 = fmaf(xi, w4.w, a3);
                }
                part[b][0] += a0; part[b][1] += a1;
                part[b][2] += a2; part[b][3] += a3;
                sm.pk[0][b][n][oq] = packbf(a0, a1);
                sm.pk[1][b][n][oq] = packbf(a2, a3);
            }
        }
    }
    float bl[BT][NSTEP];
#pragma unroll
    for (int b = 0; b < BT; ++b)
#pragma unroll
        for (int j = 0; j < 4; ++j) {
            float t = part[b][j];
#pragma unroll
            for (int off = 4; off < 64; off <<= 1) t += __shfl_xor(t, off, 64);
            part[b][j] = t;
        }
    __syncthreads();
    if (lane < 4) {
#pragma unroll
        for (int b = 0; b < BT; ++b)
#pragma unroll
            for (int j = 0; j < 4; ++j) sm.red16[wid][b][lane * 4 + j] = part[b][j];
    }
    __syncthreads();
#pragma unroll
    for (int b = 0; b < BT; ++b) {
        float sn = 0.f;
#pragma unroll
        for (int j = 0; j < 4; ++j) {
            float acc = sm.red16[0][b][oq * 4 + j];
#pragma unroll
            for (int w = 1; w < NWAVES; ++w) acc += sm.red16[w][b][oq * 4 + j];
            s[b][j] = acc * (1.0f / NROUTE);
            sn += s[b][j] * s[b][j];
        }
        sn += __shfl_xor(sn, 1, 64);
        sn += __shfl_xor(sn, 2, 64);
        float scale = sn / ((1.f + sn) * sqrtf(sn));
#pragma unroll
        for (int j = 0; j < 4; ++j) v[b][j] = s[b][j] * scale;
    }
#pragma unroll
    for (int b = 0; b < BT; ++b)
#pragma unroll
        for (int k = 0; k < NSTEP; ++k) {
            const int n = k * 128 + nbase;
            float2 u0 = unpk(sm.pk[0][b][n][oq]);
            float2 u1 = unpk(sm.pk[1][b][n][oq]);
            float d = u0.x * v[b][0] + u0.y * v[b][1] + u1.x * v[b][2] + u1.y * v[b][3];
            d += __shfl_xor(d, 1, 64);
            d += __shfl_xor(d, 2, 64);
            bl[b][k] = d;
        }
#pragma unroll
    for (int it = 1; it < 3; ++it) {
        float m[BT];
#pragma unroll
        for (int b = 0; b < BT; ++b) {
            float mm = bl[b][0];
#pragma unroll
            for (int k = 1; k < NSTEP; ++k) mm = fmaxf(mm, bl[b][k]);
#pragma unroll
            for (int off = 4; off < 64; off <<= 1) mm = fmaxf(mm, __shfl_xor(mm, off, 64));
            m[b] = mm;
        }
        __syncthreads();
        if (lane == 0) {
#pragma unroll
            for (int b = 0; b < BT; ++b) sm.sred[wid][b] = m[b];
        }
        __syncthreads();
#pragma unroll
        for (int b = 0; b < BT; ++b) {
            float mm = sm.sred[0][b];
#pragma unroll
            for (int w = 1; w < NWAVES; ++w) mm = fmaxf(mm, sm.sred[w][b]);
            m[b] = mm;
        }
        float es[BT];
#pragma unroll
        for (int b = 0; b < BT; ++b) {
            float ez = 0.f, a0 = 0, a1 = 0, a2 = 0, a3 = 0;
#pragma unroll
            for (int k = 0; k < NSTEP; ++k) {
                const int n = k * 128 + nbase;
                float ek = __expf(bl[b][k] - m[b]);
                ez += ek;
                float2 u0 = unpk(sm.pk[0][b][n][oq]);
                float2 u1 = unpk(sm.pk[1][b][n][oq]);
                a0 = fmaf(ek, u0.x, a0); a1 = fmaf(ek, u0.y, a1);
                a2 = fmaf(ek, u1.x, a2); a3 = fmaf(ek, u1.y, a3);
            }
#pragma unroll
            for (int off = 4; off < 64; off <<= 1) {
                a0 += __shfl_xor(a0, off, 64);
                a1 += __shfl_xor(a1, off, 64);
                a2 += __shfl_xor(a2, off, 64);
                a3 += __shfl_xor(a3, off, 64);
            }
            part[b][0] = a0; part[b][1] = a1; part[b][2] = a2; part[b][3] = a3;
#pragma unroll
            for (int off = 4; off < 64; off <<= 1) ez += __shfl_xor(ez, off, 64);
            es[b] = ez;
        }
        __syncthreads();
        if (lane < 4) {
#pragma unroll
            for (int b = 0; b < BT; ++b) {
#pragma unroll
                for (int j = 0; j < 4; ++j) sm.red16[wid][b][lane * 4 + j] = part[b][j];
                if (lane == 0) sm.sred[wid][b] = es[b];
            }
        }
        __syncthreads();
#pragma unroll
        for (int b = 0; b < BT; ++b) {
            float z = sm.sred[0][b];
#pragma unroll
            for (int w = 1; w < NWAVES; ++w) z += sm.sred[w][b];
            float invZ = 1.0f / z;
            float sn = 0.f;
#pragma unroll
            for (int j = 0; j < 4; ++j) {
                float acc = sm.red16[0][b][oq * 4 + j];
#pragma unroll
                for (int w = 1; w < NWAVES; ++w) acc += sm.red16[w][b][oq * 4 + j];
                s[b][j] = acc * invZ;
                sn += s[b][j] * s[b][j];
            }
            sn += __shfl_xor(sn, 1, 64);
            sn += __shfl_xor(sn, 2, 64);
            float scale = sn / ((1.f + sn) * sqrtf(sn));
#pragma unroll
            for (int j = 0; j < 4; ++j) v[b][j] = s[b][j] * scale;
        }
        if (it < 2) {
#pragma unroll
            for (int b = 0; b < BT; ++b)
#pragma unroll
                for (int k = 0; k < NSTEP; ++k) {
                    const int n = k * 128 + nbase;
                    float2 u0 = unpk(sm.pk[0][b][n][oq]);
                    float2 u1 = unpk(sm.pk[1][b][n][oq]);
                    float d = u0.x * v[b][0] + u0.y * v[b][1] + u1.x * v[b][2] + u1.y * v[b][3];
                    d += __shfl_xor(d, 1, 64);
                    d += __shfl_xor(d, 2, 64);
                    bl[b][k] += d;
                }
        }
    }
    if (tid < 4) {
#pragma unroll
        for (int b = 0; b < BT; ++b) {
            float4 o = make_float4(v[b][0], v[b][1], v[b][2], v[b][3]);
            *reinterpret_cast<float4*>(
                out + ((size_t)(c * BATCH + b0 + b) * COUT) + tid * 4) = o;
        }
    }
}

extern "C" void kernel_launch(void* const* d_in, const int* in_sizes, int n_in,
                              void* d_out, int out_size, void* d_ws, size_t ws_size,
                              hipStream_t stream) {
    const float* x  = (const float*)d_in[0];
    const float* Wt = (const float*)d_in[1];
    float* out = (float*)d_out;
    if (ws_size >= WS_NEEDED) {
        k1_priors<<<dim3(1440), dim3(256), 0, stream>>>(x, Wt, (uint4*)d_ws);
        k2_route<<<dim3(NCAPS * BATCH), dim3(192), 0, stream>>>(
            (const uint4*)d_ws, out);
    } else {
        capsule_routing_kernel<<<dim3(FGRID), dim3(T), 0, stream>>>(x, Wt, out);
    }
}

// Round 11
// 120.320 us; speedup vs baseline: 1.2931x; 1.0885x over previous
//
#include <hip/hip_runtime.h>
#include <stdint.h>

// CapsuleLayer dynamic routing. Round 11: two-kernel split, both rewritten.
//  K1 v3: o-quad layout (W frag 32 regs, uint2 stores), 4-deep rotating x
//         prefetch, bg-major XCD swizzle (x slice 1.18MB -> L2-resident).
//         Grid 2880 = 16 bg * (10 c * 18 nc), 64n x 16b per block.
//  K2 v2: oh-half layout, 128 thr/block: lane owns 8 o's -> 5-step
//         butterflies on 8 values (was 6-step on 16), dot = shfl_xor(d,1).
//  ws byte layout identical across k1/k2 (and to round 10).
//  Fallback: round-8 fused kernel if ws_size < 94.4 MB.
//
// x:  [B=256, N=1152, CIN=8] fp32 | W: [10, 1152, 8, 16] fp32
// out:[10, B, 1, 1, 16] fp32
// ws: bf16 priors [c][b][n][o]; u32 pair j = (o=2j in hi16, o=2j+1 in lo16)

constexpr int NCAPS  = 10;
constexpr int BATCH  = 256;
constexpr int NROUTE = 1152;
constexpr int CIN    = 8;
constexpr int COUT   = 16;
constexpr size_t WS_NEEDED = (size_t)NCAPS * BATCH * NROUTE * COUT * 2;  // 94.4 MB

__device__ inline uint32_t bf16rne(float f) {
    uint32_t u = __float_as_uint(f);
    return (u + 0x7fffu + ((u >> 16) & 1u)) >> 16;
}
__device__ inline uint32_t packbf(float a, float b) {
    return (bf16rne(a) << 16) | bf16rne(b);
}
__device__ inline float2 unpk(uint32_t u) {
    return make_float2(__uint_as_float(u & 0xffff0000u),
                       __uint_as_float(u << 16));
}
__device__ inline float fcomp(const float4& v, int j) {   // j compile-time
    return j == 0 ? v.x : j == 1 ? v.y : j == 2 ? v.z : v.w;
}

// ======================= K1 v3: priors =================================
// grid 2880 = 8 XCD * 360; logical = bg*180 + (c*18+nc), bg-major so each
// XCD owns 2 bg (32 b) -> x slice 1.18 MB L2-resident.
// Block: 256 thr = 4 waves; wave covers 16 n (nn=lane>>2) x 4 oq (lane&3);
// block covers n = nc*64 + wid*16 + nn, b = bg*16 + j (j=0..15).
// W frag: 8 float4 (32 regs). x: 4-deep rotating prefetch (32 regs).

__global__ __launch_bounds__(256, 2)
void k1_priors(const float* __restrict__ x, const float* __restrict__ Wt,
               uint2* __restrict__ ws) {
    const int phys    = blockIdx.x;
    const int logical = (phys & 7) * 360 + (phys >> 3);   // bijective (2880=8*360)
    const int bg = logical / 180;                         // 0..15
    const int r  = logical % 180;
    const int c  = r / 18;
    const int nc = r % 18;                                // 64-n chunk
    const int tid  = threadIdx.x;
    const int lane = tid & 63;
    const int wid  = tid >> 6;
    const int nn   = lane >> 2;                           // 0..15
    const int oq   = lane & 3;                            // 0..3
    const int n    = nc * 64 + wid * 16 + nn;
    const int b0   = bg * 16;

    // W row n, o-quad oq: float4 at i*4 + oq for i=0..7
    const float4* wp = reinterpret_cast<const float4*>(
                           Wt + ((size_t)c * NROUTE + n) * (CIN * COUT)) + oq;
    float4 wreg[8];
#pragma unroll
    for (int i = 0; i < 8; ++i) wreg[i] = wp[i * 4];

    uint2* wsc = ws + (size_t)c * BATCH * NROUTE * 4;     // uint2 units

    float4 xb[4][2];                                      // rotating 4-deep
#pragma unroll
    for (int p = 0; p < 3; ++p) {
        const float4* xp = reinterpret_cast<const float4*>(x) +
                           ((size_t)(b0 + p) * NROUTE + n) * 2;
        xb[p][0] = xp[0];
        xb[p][1] = xp[1];
    }
#pragma unroll
    for (int j = 0; j < 16; ++j) {
        if (j + 3 < 16) {
            const float4* xp = reinterpret_cast<const float4*>(x) +
                               ((size_t)(b0 + j + 3) * NROUTE + n) * 2;
            xb[(j + 3) & 3][0] = xp[0];
            xb[(j + 3) & 3][1] = xp[1];
        }
        float a0 = 0.f, a1 = 0.f, a2 = 0.f, a3 = 0.f;
#pragma unroll
        for (int i = 0; i < 8; ++i) {
            const float xi = fcomp(xb[j & 3][i >> 2], i & 3);
            const float4 w = wreg[i];
            a0 = fmaf(xi, w.x, a0); a1 = fmaf(xi, w.y, a1);
            a2 = fmaf(xi, w.z, a2); a3 = fmaf(xi, w.w, a3);
        }
        wsc[((size_t)(b0 + j) * NROUTE + n) * 4 + oq] =
            make_uint2(packbf(a0, a1), packbf(a2, a3));
    }
}

// ======================= K2 v2: routing ================================
// grid 2560 = (c,b); block 128 thr = 2 waves. nn=tid>>1 (0..63), oh=tid&1.
// Thread owns n = nn+64k (k=0..17), o in [8oh, 8oh+8): pk[18] uint4.
// Reductions: in-thread (18) -> shfl_xor {2,4,8,16,32} over nn -> LDS x2
// waves. Full 16-o dots complete with one shfl_xor(d,1).

#define UNPK8(U, q)                                                         \
    {                                                                       \
        float2 t0 = unpk((U).x), t1 = unpk((U).y);                          \
        float2 t2 = unpk((U).z), t3 = unpk((U).w);                          \
        q[0] = t0.x; q[1] = t0.y; q[2] = t1.x; q[3] = t1.y;                 \
        q[4] = t2.x; q[5] = t2.y; q[6] = t3.x; q[7] = t3.y;                 \
    }

__global__ __launch_bounds__(128, 2)
void k2_route(const uint4* __restrict__ P4, float* __restrict__ out) {
    const int blk = blockIdx.x;
    const int c = blk >> 8;
    const int b = blk & 255;
    const int tid  = threadIdx.x;
    const int lane = tid & 63;
    const int wid  = tid >> 6;
    const int nn   = tid >> 1;        // 0..63
    const int oh   = tid & 1;         // o-half

    __shared__ float redv[2][16];
    __shared__ float redz[2];

    const uint4* Pb = P4 + (size_t)(c * BATCH + b) * NROUTE * 2;
    uint4 pk[18];
#pragma unroll
    for (int k = 0; k < 18; ++k)
        pk[k] = Pb[(size_t)(nn + 64 * k) * 2 + oh];

    float q[8], v[8], s[8];

    // ---- iter 0: uniform probs -------------------------------------------
    float part[8];
#pragma unroll
    for (int j = 0; j < 8; ++j) part[j] = 0.f;
#pragma unroll
    for (int k = 0; k < 18; ++k) {
        UNPK8(pk[k], q)
#pragma unroll
        for (int j = 0; j < 8; ++j) part[j] += q[j];
    }
#pragma unroll
    for (int j = 0; j < 8; ++j) {
#pragma unroll
        for (int off = 2; off < 64; off <<= 1) part[j] += __shfl_xor(part[j], off, 64);
    }
    __syncthreads();
    if (lane < 2) {
#pragma unroll
        for (int j = 0; j < 8; ++j) redv[wid][lane * 8 + j] = part[j];
    }
    __syncthreads();
    {
        float sn = 0.f;
#pragma unroll
        for (int j = 0; j < 8; ++j) {
            s[j] = (redv[0][oh * 8 + j] + redv[1][oh * 8 + j]) * (1.0f / NROUTE);
            sn += s[j] * s[j];
        }
        sn += __shfl_xor(sn, 1, 64);
        float scale = sn / ((1.f + sn) * sqrtf(sn));
#pragma unroll
        for (int j = 0; j < 8; ++j) v[j] = s[j] * scale;
    }
    float bl[18];
#pragma unroll
    for (int k = 0; k < 18; ++k) {
        UNPK8(pk[k], q)
        float d = 0.f;
#pragma unroll
        for (int j = 0; j < 8; ++j) d = fmaf(q[j], v[j], d);
        d += __shfl_xor(d, 1, 64);     // add other o-half
        bl[k] = d;
    }

    // ---- iters 1, 2 -------------------------------------------------------
#pragma unroll
    for (int it = 1; it < 3; ++it) {
        float mm = bl[0];
#pragma unroll
        for (int k = 1; k < 18; ++k) mm = fmaxf(mm, bl[k]);
#pragma unroll
        for (int off = 2; off < 64; off <<= 1) mm = fmaxf(mm, __shfl_xor(mm, off, 64));
        __syncthreads();
        if (lane == 0) redz[wid] = mm;
        __syncthreads();
        mm = fmaxf(redz[0], redz[1]);

        float ez = 0.f, acc[8];
#pragma unroll
        for (int j = 0; j < 8; ++j) acc[j] = 0.f;
#pragma unroll
        for (int k = 0; k < 18; ++k) {
            float e = __expf(bl[k] - mm);
            ez += e;
            UNPK8(pk[k], q)
#pragma unroll
            for (int j = 0; j < 8; ++j) acc[j] = fmaf(e, q[j], acc[j]);
        }
#pragma unroll
        for (int j = 0; j < 8; ++j) {
#pragma unroll
            for (int off = 2; off < 64; off <<= 1) acc[j] += __shfl_xor(acc[j], off, 64);
        }
#pragma unroll
        for (int off = 2; off < 64; off <<= 1) ez += __shfl_xor(ez, off, 64);
        __syncthreads();
        if (lane < 2) {
#pragma unroll
            for (int j = 0; j < 8; ++j) redv[wid][lane * 8 + j] = acc[j];
            if (lane == 0) redz[wid] = ez;
        }
        __syncthreads();
        const float invZ = 1.0f / (redz[0] + redz[1]);
        float sn = 0.f;
#pragma unroll
        for (int j = 0; j < 8; ++j) {
            s[j] = (redv[0][oh * 8 + j] + redv[1][oh * 8 + j]) * invZ;
            sn += s[j] * s[j];
        }
        sn += __shfl_xor(sn, 1, 64);
        float scale = sn / ((1.f + sn) * sqrtf(sn));
#pragma unroll
        for (int j = 0; j < 8; ++j) v[j] = s[j] * scale;

        if (it < 2) {
#pragma unroll
            for (int k = 0; k < 18; ++k) {
                UNPK8(pk[k], q)
                float d = 0.f;
#pragma unroll
                for (int j = 0; j < 8; ++j) d = fmaf(q[j], v[j], d);
                d += __shfl_xor(d, 1, 64);
                bl[k] += d;
            }
        }
    }

    if (tid < 2) {                       // tid==oh, nn=0, wave 0
        float* ob = out + (size_t)(c * BATCH + b) * COUT + oh * 8;
        *reinterpret_cast<float4*>(ob + 0) = make_float4(v[0], v[1], v[2], v[3]);
        *reinterpret_cast<float4*>(ob + 4) = make_float4(v[4], v[5], v[6], v[7]);
    }
}

// ======================= fallback: round-8 fused kernel =================
constexpr int T      = 512;
constexpr int NWAVES = T / 64;
constexpr int BT     = 2;
constexpr int NSTEP  = NROUTE / (NWAVES * 16);   // 9
constexpr int BG     = BATCH / BT;               // 128
constexpr int FGRID  = NCAPS * BG;               // 1280
constexpr int CPX    = FGRID / 8;                // 160

struct SMem {
    uint32_t pk[2][BT][NROUTE][4];
    float red16[NWAVES][BT][COUT];
    float sred[NWAVES][BT];
};

#define LOADW(KK, BUF) do {                                                      \
    const int n_ = (KK) * 128 + nbase;                                           \
    const float4* wp_ = reinterpret_cast<const float4*>(Wc + (size_t)n_ * 128) + oq; \
    _Pragma("unroll")                                                            \
    for (int i_ = 0; i_ < 8; ++i_) wreg[BUF][i_] = wp_[i_ * 4];                  \
} while (0)

#define LOADX(KK, BUF) do {                                                      \
    const int n_ = (KK) * 128 + nbase;                                           \
    _Pragma("unroll")                                                            \
    for (int b_ = 0; b_ < BT; ++b_) {                                            \
        const float4* xp_ = reinterpret_cast<const float4*>(                     \
            xbase + (size_t)b_ * (NROUTE * CIN) + (size_t)n_ * CIN);             \
        xreg[BUF][b_ * 2 + 0] = xp_[0];                                          \
        xreg[BUF][b_ * 2 + 1] = xp_[1];                                          \
    }                                                                            \
} while (0)

__global__ __launch_bounds__(T, 2)
void capsule_routing_kernel(const float* __restrict__ x,
                            const float* __restrict__ Wt,
                            float* __restrict__ out) {
    __shared__ SMem sm;
    const int phys    = blockIdx.x;
    const int logical = (phys & 7) * CPX + (phys >> 3);
    const int c  = logical / BG;
    const int b0 = (logical % BG) * BT;
    const int tid  = threadIdx.x;
    const int lane = tid & 63;
    const int wid  = tid >> 6;
    const int nn   = lane >> 2;
    const int oq   = lane & 3;
    const int nbase = wid * 16 + nn;

    const float* Wc    = Wt + (size_t)c * NROUTE * (CIN * COUT);
    const float* xbase = x + (size_t)b0 * NROUTE * CIN;

    float part[BT][4], s[BT][4], v[BT][4];
    {
        float4 wreg[2][8];
        float4 xreg[2][BT * 2];
#pragma unroll
        for (int b = 0; b < BT; ++b)
#pragma unroll
            for (int j = 0; j < 4; ++j) part[b][j] = 0.f;
        LOADW(0, 0);
        LOADX(0, 0);
#pragma unroll
        for (int k = 0; k < NSTEP; ++k) {
            const int cur = k & 1;
            if (k + 1 < NSTEP) {
                if (cur == 0) { LOADW(k + 1, 1); LOADX(k + 1, 1); }
                else          { LOADW(k + 1, 0); LOADX(k + 1, 0); }
            }
            const int n = k * 128 + nbase;
#pragma unroll
            for (int b = 0; b < BT; ++b) {
                float a0 = 0.f, a1 = 0.f, a2 = 0.f, a3 = 0.f;
#pragma unroll
                for (int i = 0; i < 8; ++i) {
                    float4 w4 = wreg[cur][i];
                    float xi = fcomp(xreg[cur][b * 2 + (i >> 2)], i & 3);
                    a0 = fmaf(xi, w4.x, a0);
                    a1 = fmaf(xi, w4.y, a1);
                    a2 = fmaf(xi, w4.z, a2);
                    a3 = fmaf(xi, w4.w, a3);
                }
                part[b][0] += a0; part[b][1] += a1;
                part[b][2] += a2; part[b][3] += a3;
                sm.pk[0][b][n][oq] = packbf(a0, a1);
                sm.pk[1][b][n][oq] = packbf(a2, a3);
            }
        }
    }
    float bl[BT][NSTEP];
#pragma unroll
    for (int b = 0; b < BT; ++b)
#pragma unroll
        for (int j = 0; j < 4; ++j) {
            float t = part[b][j];
#pragma unroll
            for (int off = 4; off < 64; off <<= 1) t += __shfl_xor(t, off, 64);
            part[b][j] = t;
        }
    __syncthreads();
    if (lane < 4) {
#pragma unroll
        for (int b = 0; b < BT; ++b)
#pragma unroll
            for (int j = 0; j < 4; ++j) sm.red16[wid][b][lane * 4 + j] = part[b][j];
    }
    __syncthreads();
#pragma unroll
    for (int b = 0; b < BT; ++b) {
        float sn = 0.f;
#pragma unroll
        for (int j = 0; j < 4; ++j) {
            float acc = sm.red16[0][b][oq * 4 + j];
#pragma unroll
            for (int w = 1; w < NWAVES; ++w) acc += sm.red16[w][b][oq * 4 + j];
            s[b][j] = acc * (1.0f / NROUTE);
            sn += s[b][j] * s[b][j];
        }
        sn += __shfl_xor(sn, 1, 64);
        sn += __shfl_xor(sn, 2, 64);
        float scale = sn / ((1.f + sn) * sqrtf(sn));
#pragma unroll
        for (int j = 0; j < 4; ++j) v[b][j] = s[b][j] * scale;
    }
#pragma unroll
    for (int b = 0; b < BT; ++b)
#pragma unroll
        for (int k = 0; k < NSTEP; ++k) {
            const int n = k * 128 + nbase;
            float2 u0 = unpk(sm.pk[0][b][n][oq]);
            float2 u1 = unpk(sm.pk[1][b][n][oq]);
            float d = u0.x * v[b][0] + u0.y * v[b][1] + u1.x * v[b][2] + u1.y * v[b][3];
            d += __shfl_xor(d, 1, 64);
            d += __shfl_xor(d, 2, 64);
            bl[b][k] = d;
        }
#pragma unroll
    for (int it = 1; it < 3; ++it) {
        float m[BT];
#pragma unroll
        for (int b = 0; b < BT; ++b) {
            float mm = bl[b][0];
#pragma unroll
            for (int k = 1; k < NSTEP; ++k) mm = fmaxf(mm, bl[b][k]);
#pragma unroll
            for (int off = 4; off < 64; off <<= 1) mm = fmaxf(mm, __shfl_xor(mm, off, 64));
            m[b] = mm;
        }
        __syncthreads();
        if (lane == 0) {
#pragma unroll
            for (int b = 0; b < BT; ++b) sm.sred[wid][b] = m[b];
        }
        __syncthreads();
#pragma unroll
        for (int b = 0; b < BT; ++b) {
            float mm = sm.sred[0][b];
#pragma unroll
            for (int w = 1; w < NWAVES; ++w) mm = fmaxf(mm, sm.sred[w][b]);
            m[b] = mm;
        }
        float es[BT];
#pragma unroll
        for (int b = 0; b < BT; ++b) {
            float ez = 0.f, a0 = 0, a1 = 0, a2 = 0, a3 = 0;
#pragma unroll
            for (int k = 0; k < NSTEP; ++k) {
                const int n = k * 128 + nbase;
                float ek = __expf(bl[b][k] - m[b]);
                ez += ek;
                float2 u0 = unpk(sm.pk[0][b][n][oq]);
                float2 u1 = unpk(sm.pk[1][b][n][oq]);
                a0 = fmaf(ek, u0.x, a0); a1 = fmaf(ek, u0.y, a1);
                a2 = fmaf(ek, u1.x, a2); a3 = fmaf(ek, u1.y, a3);
            }
#pragma unroll
            for (int off = 4; off < 64; off <<= 1) {
                a0 += __shfl_xor(a0, off, 64);
                a1 += __shfl_xor(a1, off, 64);
                a2 += __shfl_xor(a2, off, 64);
                a3 += __shfl_xor(a3, off, 64);
            }
            part[b][0] = a0; part[b][1] = a1; part[b][2] = a2; part[b][3] = a3;
#pragma unroll
            for (int off = 4; off < 64; off <<= 1) ez += __shfl_xor(ez, off, 64);
            es[b] = ez;
        }
        __syncthreads();
        if (lane < 4) {
#pragma unroll
            for (int b = 0; b < BT; ++b) {
#pragma unroll
                for (int j = 0; j < 4; ++j) sm.red16[wid][b][lane * 4 + j] = part[b][j];
                if (lane == 0) sm.sred[wid][b] = es[b];
            }
        }
        __syncthreads();
#pragma unroll
        for (int b = 0; b < BT; ++b) {
            float z = sm.sred[0][b];
#pragma unroll
            for (int w = 1; w < NWAVES; ++w) z += sm.sred[w][b];
            float invZ = 1.0f / z;
            float sn = 0.f;
#pragma unroll
            for (int j = 0; j < 4; ++j) {
                float acc = sm.red16[0][b][oq * 4 + j];
#pragma unroll
                for (int w = 1; w < NWAVES; ++w) acc += sm.red16[w][b][oq * 4 + j];
                s[b][j] = acc * invZ;
                sn += s[b][j] * s[b][j];
            }
            sn += __shfl_xor(sn, 1, 64);
            sn += __shfl_xor(sn, 2, 64);
            float scale = sn / ((1.f + sn) * sqrtf(sn));
#pragma unroll
            for (int j = 0; j < 4; ++j) v[b][j] = s[b][j] * scale;
        }
        if (it < 2) {
#pragma unroll
            for (int b = 0; b < BT; ++b)
#pragma unroll
                for (int k = 0; k < NSTEP; ++k) {
                    const int n = k * 128 + nbase;
                    float2 u0 = unpk(sm.pk[0][b][n][oq]);
                    float2 u1 = unpk(sm.pk[1][b][n][oq]);
                    float d = u0.x * v[b][0] + u0.y * v[b][1] + u1.x * v[b][2] + u1.y * v[b][3];
                    d += __shfl_xor(d, 1, 64);
                    d += __shfl_xor(d, 2, 64);
                    bl[b][k] += d;
                }
        }
    }
    if (tid < 4) {
#pragma unroll
        for (int b = 0; b < BT; ++b) {
            float4 o = make_float4(v[b][0], v[b][1], v[b][2], v[b][3]);
            *reinterpret_cast<float4*>(
                out + ((size_t)(c * BATCH + b0 + b) * COUT) + tid * 4) = o;
        }
    }
}

extern "C" void kernel_launch(void* const* d_in, const int* in_sizes, int n_in,
                              void* d_out, int out_size, void* d_ws, size_t ws_size,
                              hipStream_t stream) {
    const float* x  = (const float*)d_in[0];
    const float* Wt = (const float*)d_in[1];
    float* out = (float*)d_out;
    if (ws_size >= WS_NEEDED) {
        k1_priors<<<dim3(2880), dim3(256), 0, stream>>>(x, Wt, (uint2*)d_ws);
        k2_route<<<dim3(NCAPS * BATCH), dim3(128), 0, stream>>>(
            (const uint4*)d_ws, out);
    } else {
        capsule_routing_kernel<<<dim3(FGRID), dim3(T), 0, stream>>>(x, Wt, out);
    }
}

// Round 13
// 116.145 us; speedup vs baseline: 1.3395x; 1.0359x over previous
//
#include <hip/hip_runtime.h>
#include <stdint.h>

// CapsuleLayer dynamic routing. Round 13 (= round 12 with a compilable pin):
//  K1 v4: o-quad, uint2 stores, 4-deep x prefetch, bg-major XCD swizzle,
//         + asm scalar-component pin on the 8 W float4 so the backend
//         cannot rematerialize them (rounds 9-11: VGPR 28-48, W re-loaded
//         every j -> ~1.5 GB L1/L2 traffic = the 43-46 us).
//         NOTE: "+v" on float4 is unsupported (tied indirect register);
//         pin per-component scalars instead.
//  K2: byte-identical to round 11 (clean attribution).
//  Fallback: round-8 fused kernel if ws_size < 94.4 MB.
//
// x:  [B=256, N=1152, CIN=8] fp32 | W: [10, 1152, 8, 16] fp32
// out:[10, B, 1, 1, 16] fp32
// ws: bf16 priors [c][b][n][o]; u32 pair j = (o=2j in hi16, o=2j+1 in lo16)

constexpr int NCAPS  = 10;
constexpr int BATCH  = 256;
constexpr int NROUTE = 1152;
constexpr int CIN    = 8;
constexpr int COUT   = 16;
constexpr size_t WS_NEEDED = (size_t)NCAPS * BATCH * NROUTE * COUT * 2;  // 94.4 MB

__device__ inline uint32_t bf16rne(float f) {
    uint32_t u = __float_as_uint(f);
    return (u + 0x7fffu + ((u >> 16) & 1u)) >> 16;
}
__device__ inline uint32_t packbf(float a, float b) {
    return (bf16rne(a) << 16) | bf16rne(b);
}
__device__ inline float2 unpk(uint32_t u) {
    return make_float2(__uint_as_float(u & 0xffff0000u),
                       __uint_as_float(u << 16));
}
__device__ inline float fcomp(const float4& v, int j) {   // j compile-time
    return j == 0 ? v.x : j == 1 ? v.y : j == 2 ? v.z : v.w;
}
// Opaque pin on scalar components: values become asm outputs -> cannot be
// rematerialized, must stay resident in VGPRs across their live range.
__device__ inline void pin4(float4& v) {
    asm volatile("" : "+v"(v.x), "+v"(v.y), "+v"(v.z), "+v"(v.w));
}

// ======================= K1 v4: priors =================================
// grid 2880 = 8 XCD * 360; logical = bg*180 + (c*18+nc), bg-major so each
// XCD owns 2 bg (32 b) -> x slice 1.18 MB L2-resident.
// Block: 256 thr = 4 waves; wave covers 16 n (nn=lane>>2) x 4 oq (lane&3);
// block covers n = nc*64 + wid*16 + nn, b = bg*16 + j (j=0..15).
// W frag: 8 float4 (32 regs, asm-pinned). x: 4-deep rotating prefetch.

__global__ __launch_bounds__(256, 1)
void k1_priors(const float* __restrict__ x, const float* __restrict__ Wt,
               uint2* __restrict__ ws) {
    const int phys    = blockIdx.x;
    const int logical = (phys & 7) * 360 + (phys >> 3);   // bijective (2880=8*360)
    const int bg = logical / 180;                         // 0..15
    const int r  = logical % 180;
    const int c  = r / 18;
    const int nc = r % 18;                                // 64-n chunk
    const int tid  = threadIdx.x;
    const int lane = tid & 63;
    const int wid  = tid >> 6;
    const int nn   = lane >> 2;                           // 0..15
    const int oq   = lane & 3;                            // 0..3
    const int n    = nc * 64 + wid * 16 + nn;
    const int b0   = bg * 16;

    // W row n, o-quad oq: float4 at i*4 + oq for i=0..7; pinned in VGPRs.
    const float4* wp = reinterpret_cast<const float4*>(
                           Wt + ((size_t)c * NROUTE + n) * (CIN * COUT)) + oq;
    float4 wreg[8];
#pragma unroll
    for (int i = 0; i < 8; ++i) wreg[i] = wp[i * 4];
#pragma unroll
    for (int i = 0; i < 8; ++i) pin4(wreg[i]);

    uint2* wsc = ws + (size_t)c * BATCH * NROUTE * 4;     // uint2 units

    float4 xb[4][2];                                      // rotating 4-deep
#pragma unroll
    for (int p = 0; p < 3; ++p) {
        const float4* xp = reinterpret_cast<const float4*>(x) +
                           ((size_t)(b0 + p) * NROUTE + n) * 2;
        xb[p][0] = xp[0];
        xb[p][1] = xp[1];
    }
#pragma unroll
    for (int j = 0; j < 16; ++j) {
        if (j + 3 < 16) {
            const float4* xp = reinterpret_cast<const float4*>(x) +
                               ((size_t)(b0 + j + 3) * NROUTE + n) * 2;
            xb[(j + 3) & 3][0] = xp[0];
            xb[(j + 3) & 3][1] = xp[1];
        }
        float a0 = 0.f, a1 = 0.f, a2 = 0.f, a3 = 0.f;
#pragma unroll
        for (int i = 0; i < 8; ++i) {
            const float xi = fcomp(xb[j & 3][i >> 2], i & 3);
            const float4 w = wreg[i];
            a0 = fmaf(xi, w.x, a0); a1 = fmaf(xi, w.y, a1);
            a2 = fmaf(xi, w.z, a2); a3 = fmaf(xi, w.w, a3);
        }
        wsc[((size_t)(b0 + j) * NROUTE + n) * 4 + oq] =
            make_uint2(packbf(a0, a1), packbf(a2, a3));
    }
}

// ======================= K2 v2: routing (unchanged from round 11) ======
#define UNPK8(U, q)                                                         \
    {                                                                       \
        float2 t0 = unpk((U).x), t1 = unpk((U).y);                          \
        float2 t2 = unpk((U).z), t3 = unpk((U).w);                          \
        q[0] = t0.x; q[1] = t0.y; q[2] = t1.x; q[3] = t1.y;                 \
        q[4] = t2.x; q[5] = t2.y; q[6] = t3.x; q[7] = t3.y;                 \
    }

__global__ __launch_bounds__(128, 2)
void k2_route(const uint4* __restrict__ P4, float* __restrict__ out) {
    const int blk = blockIdx.x;
    const int c = blk >> 8;
    const int b = blk & 255;
    const int tid  = threadIdx.x;
    const int lane = tid & 63;
    const int wid  = tid >> 6;
    const int nn   = tid >> 1;        // 0..63
    const int oh   = tid & 1;         // o-half

    __shared__ float redv[2][16];
    __shared__ float redz[2];

    const uint4* Pb = P4 + (size_t)(c * BATCH + b) * NROUTE * 2;
    uint4 pk[18];
#pragma unroll
    for (int k = 0; k < 18; ++k)
        pk[k] = Pb[(size_t)(nn + 64 * k) * 2 + oh];

    float q[8], v[8], s[8];

    float part[8];
#pragma unroll
    for (int j = 0; j < 8; ++j) part[j] = 0.f;
#pragma unroll
    for (int k = 0; k < 18; ++k) {
        UNPK8(pk[k], q)
#pragma unroll
        for (int j = 0; j < 8; ++j) part[j] += q[j];
    }
#pragma unroll
    for (int j = 0; j < 8; ++j) {
#pragma unroll
        for (int off = 2; off < 64; off <<= 1) part[j] += __shfl_xor(part[j], off, 64);
    }
    __syncthreads();
    if (lane < 2) {
#pragma unroll
        for (int j = 0; j < 8; ++j) redv[wid][lane * 8 + j] = part[j];
    }
    __syncthreads();
    {
        float sn = 0.f;
#pragma unroll
        for (int j = 0; j < 8; ++j) {
            s[j] = (redv[0][oh * 8 + j] + redv[1][oh * 8 + j]) * (1.0f / NROUTE);
            sn += s[j] * s[j];
        }
        sn += __shfl_xor(sn, 1, 64);
        float scale = sn / ((1.f + sn) * sqrtf(sn));
#pragma unroll
        for (int j = 0; j < 8; ++j) v[j] = s[j] * scale;
    }
    float bl[18];
#pragma unroll
    for (int k = 0; k < 18; ++k) {
        UNPK8(pk[k], q)
        float d = 0.f;
#pragma unroll
        for (int j = 0; j < 8; ++j) d = fmaf(q[j], v[j], d);
        d += __shfl_xor(d, 1, 64);     // add other o-half
        bl[k] = d;
    }

#pragma unroll
    for (int it = 1; it < 3; ++it) {
        float mm = bl[0];
#pragma unroll
        for (int k = 1; k < 18; ++k) mm = fmaxf(mm, bl[k]);
#pragma unroll
        for (int off = 2; off < 64; off <<= 1) mm = fmaxf(mm, __shfl_xor(mm, off, 64));
        __syncthreads();
        if (lane == 0) redz[wid] = mm;
        __syncthreads();
        mm = fmaxf(redz[0], redz[1]);

        float ez = 0.f, acc[8];
#pragma unroll
        for (int j = 0; j < 8; ++j) acc[j] = 0.f;
#pragma unroll
        for (int k = 0; k < 18; ++k) {
            float e = __expf(bl[k] - mm);
            ez += e;
            UNPK8(pk[k], q)
#pragma unroll
            for (int j = 0; j < 8; ++j) acc[j] = fmaf(e, q[j], acc[j]);
        }
#pragma unroll
        for (int j = 0; j < 8; ++j) {
#pragma unroll
            for (int off = 2; off < 64; off <<= 1) acc[j] += __shfl_xor(acc[j], off, 64);
        }
#pragma unroll
        for (int off = 2; off < 64; off <<= 1) ez += __shfl_xor(ez, off, 64);
        __syncthreads();
        if (lane < 2) {
#pragma unroll
            for (int j = 0; j < 8; ++j) redv[wid][lane * 8 + j] = acc[j];
            if (lane == 0) redz[wid] = ez;
        }
        __syncthreads();
        const float invZ = 1.0f / (redz[0] + redz[1]);
        float sn = 0.f;
#pragma unroll
        for (int j = 0; j < 8; ++j) {
            s[j] = (redv[0][oh * 8 + j] + redv[1][oh * 8 + j]) * invZ;
            sn += s[j] * s[j];
        }
        sn += __shfl_xor(sn, 1, 64);
        float scale = sn / ((1.f + sn) * sqrtf(sn));
#pragma unroll
        for (int j = 0; j < 8; ++j) v[j] = s[j] * scale;

        if (it < 2) {
#pragma unroll
            for (int k = 0; k < 18; ++k) {
                UNPK8(pk[k], q)
                float d = 0.f;
#pragma unroll
                for (int j = 0; j < 8; ++j) d = fmaf(q[j], v[j], d);
                d += __shfl_xor(d, 1, 64);
                bl[k] += d;
            }
        }
    }

    if (tid < 2) {                       // tid==oh, nn=0, wave 0
        float* ob = out + (size_t)(c * BATCH + b) * COUT + oh * 8;
        *reinterpret_cast<float4*>(ob + 0) = make_float4(v[0], v[1], v[2], v[3]);
        *reinterpret_cast<float4*>(ob + 4) = make_float4(v[4], v[5], v[6], v[7]);
    }
}

// ======================= fallback: round-8 fused kernel =================
constexpr int T      = 512;
constexpr int NWAVES = T / 64;
constexpr int BT     = 2;
constexpr int NSTEP  = NROUTE / (NWAVES * 16);   // 9
constexpr int BG     = BATCH / BT;               // 128
constexpr int FGRID  = NCAPS * BG;               // 1280
constexpr int CPX    = FGRID / 8;                // 160

struct SMem {
    uint32_t pk[2][BT][NROUTE][4];
    float red16[NWAVES][BT][COUT];
    float sred[NWAVES][BT];
};

#define LOADW(KK, BUF) do {                                                      \
    const int n_ = (KK) * 128 + nbase;                                           \
    const float4* wp_ = reinterpret_cast<const float4*>(Wc + (size_t)n_ * 128) + oq; \
    _Pragma("unroll")                                                            \
    for (int i_ = 0; i_ < 8; ++i_) wreg[BUF][i_] = wp_[i_ * 4];                  \
} while (0)

#define LOADX(KK, BUF) do {                                                      \
    const int n_ = (KK) * 128 + nbase;                                           \
    _Pragma("unroll")                                                            \
    for (int b_ = 0; b_ < BT; ++b_) {                                            \
        const float4* xp_ = reinterpret_cast<const float4*>(                     \
            xbase + (size_t)b_ * (NROUTE * CIN) + (size_t)n_ * CIN);             \
        xreg[BUF][b_ * 2 + 0] = xp_[0];                                          \
        xreg[BUF][b_ * 2 + 1] = xp_[1];                                          \
    }                                                                            \
} while (0)

__global__ __launch_bounds__(T, 2)
void capsule_routing_kernel(const float* __restrict__ x,
                            const float* __restrict__ Wt,
                            float* __restrict__ out) {
    __shared__ SMem sm;
    const int phys    = blockIdx.x;
    const int logical = (phys & 7) * CPX + (phys >> 3);
    const int c  = logical / BG;
    const int b0 = (logical % BG) * BT;
    const int tid  = threadIdx.x;
    const int lane = tid & 63;
    const int wid  = tid >> 6;
    const int nn   = lane >> 2;
    const int oq   = lane & 3;
    const int nbase = wid * 16 + nn;

    const float* Wc    = Wt + (size_t)c * NROUTE * (CIN * COUT);
    const float* xbase = x + (size_t)b0 * NROUTE * CIN;

    float part[BT][4], s[BT][4], v[BT][4];
    {
        float4 wreg[2][8];
        float4 xreg[2][BT * 2];
#pragma unroll
        for (int b = 0; b < BT; ++b)
#pragma unroll
            for (int j = 0; j < 4; ++j) part[b][j] = 0.f;
        LOADW(0, 0);
        LOADX(0, 0);
#pragma unroll
        for (int k = 0; k < NSTEP; ++k) {
            const int cur = k & 1;
            if (k + 1 < NSTEP) {
                if (cur == 0) { LOADW(k + 1, 1); LOADX(k + 1, 1); }
                else          { LOADW(k + 1, 0); LOADX(k + 1, 0); }
            }
            const int n = k * 128 + nbase;
#pragma unroll
            for (int b = 0; b < BT; ++b) {
                float a0 = 0.f, a1 = 0.f, a2 = 0.f, a3 = 0.f;
#pragma unroll
                for (int i = 0; i < 8; ++i) {
                    float4 w4 = wreg[cur][i];
                    float xi = fcomp(xreg[cur][b * 2 + (i >> 2)], i & 3);
                    a0 = fmaf(xi, w4.x, a0);
                    a1 = fmaf(xi, w4.y, a1);
                    a2 = fmaf(xi, w4.z, a2);
                    a3 = fmaf(xi, w4.w, a3);
                }
                part[b][0] += a0; part[b][1] += a1;
                part[b][2] += a2; part[b][3] += a3;
                sm.pk[0][b][n][oq] = packbf(a0, a1);
                sm.pk[1][b][n][oq] = packbf(a2, a3);
            }
        }
    }
    float bl[BT][NSTEP];
#pragma unroll
    for (int b = 0; b < BT; ++b)
#pragma unroll
        for (int j = 0; j < 4; ++j) {
            float t = part[b][j];
#pragma unroll
            for (int off = 4; off < 64; off <<= 1) t += __shfl_xor(t, off, 64);
            part[b][j] = t;
        }
    __syncthreads();
    if (lane < 4) {
#pragma unroll
        for (int b = 0; b < BT; ++b)
#pragma unroll
            for (int j = 0; j < 4; ++j) sm.red16[wid][b][lane * 4 + j] = part[b][j];
    }
    __syncthreads();
#pragma unroll
    for (int b = 0; b < BT; ++b) {
        float sn = 0.f;
#pragma unroll
        for (int j = 0; j < 4; ++j) {
            float acc = sm.red16[0][b][oq * 4 + j];
#pragma unroll
            for (int w = 1; w < NWAVES; ++w) acc += sm.red16[w][b][oq * 4 + j];
            s[b][j] = acc * (1.0f / NROUTE);
            sn += s[b][j] * s[b][j];
        }
        sn += __shfl_xor(sn, 1, 64);
        sn += __shfl_xor(sn, 2, 64);
        float scale = sn / ((1.f + sn) * sqrtf(sn));
#pragma unroll
        for (int j = 0; j < 4; ++j) v[b][j] = s[b][j] * scale;
    }
#pragma unroll
    for (int b = 0; b < BT; ++b)
#pragma unroll
        for (int k = 0; k < NSTEP; ++k) {
            const int n = k * 128 + nbase;
            float2 u0 = unpk(sm.pk[0][b][n][oq]);
            float2 u1 = unpk(sm.pk[1][b][n][oq]);
            float d = u0.x * v[b][0] + u0.y * v[b][1] + u1.x * v[b][2] + u1.y * v[b][3];
            d += __shfl_xor(d, 1, 64);
            d += __shfl_xor(d, 2, 64);
            bl[b][k] = d;
        }
#pragma unroll
    for (int it = 1; it < 3; ++it) {
        float m[BT];
#pragma unroll
        for (int b = 0; b < BT; ++b) {
            float mm = bl[b][0];
#pragma unroll
            for (int k = 1; k < NSTEP; ++k) mm = fmaxf(mm, bl[b][k]);
#pragma unroll
            for (int off = 4; off < 64; off <<= 1) mm = fmaxf(mm, __shfl_xor(mm, off, 64));
            m[b] = mm;
        }
        __syncthreads();
        if (lane == 0) {
#pragma unroll
            for (int b = 0; b < BT; ++b) sm.sred[wid][b] = m[b];
        }
        __syncthreads();
#pragma unroll
        for (int b = 0; b < BT; ++b) {
            float mm = sm.sred[0][b];
#pragma unroll
            for (int w = 1; w < NWAVES; ++w) mm = fmaxf(mm, sm.sred[w][b]);
            m[b] = mm;
        }
        float es[BT];
#pragma unroll
        for (int b = 0; b < BT; ++b) {
            float ez = 0.f, a0 = 0, a1 = 0, a2 = 0, a3 = 0;
#pragma unroll
            for (int k = 0; k < NSTEP; ++k) {
                const int n = k * 128 + nbase;
                float ek = __expf(bl[b][k] - m[b]);
                ez += ek;
                float2 u0 = unpk(sm.pk[0][b][n][oq]);
                float2 u1 = unpk(sm.pk[1][b][n][oq]);
                a0 = fmaf(ek, u0.x, a0); a1 = fmaf(ek, u0.y, a1);
                a2 = fmaf(ek, u1.x, a2); a3 = fmaf(ek, u1.y, a3);
            }
#pragma unroll
            for (int off = 4; off < 64; off <<= 1) {
                a0 += __shfl_xor(a0, off, 64);
                a1 += __shfl_xor(a1, off, 64);
                a2 += __shfl_xor(a2, off, 64);
                a3 += __shfl_xor(a3, off, 64);
            }
            part[b][0] = a0; part[b][1] = a1; part[b][2] = a2; part[b][3] = a3;
#pragma unroll
            for (int off = 4; off < 64; off <<= 1) ez += __shfl_xor(ez, off, 64);
            es[b] = ez;
        }
        __syncthreads();
        if (lane < 4) {
#pragma unroll
            for (int b = 0; b < BT; ++b) {
#pragma unroll
                for (int j = 0; j < 4; ++j) sm.red16[wid][b][lane * 4 + j] = part[b][j];
                if (lane == 0) sm.sred[wid][b] = es[b];
            }
        }
        __syncthreads();
#pragma unroll
    for (int b = 0; b < BT; ++b) {
            float z = sm.sred[0][b];
#pragma unroll
            for (int w = 1; w < NWAVES; ++w) z += sm.sred[w][b];
            float invZ = 1.0f / z;
            float sn = 0.f;
#pragma unroll
            for (int j = 0; j < 4; ++j) {
                float acc = sm.red16[0][b][oq * 4 + j];
#pragma unroll
                for (int w = 1; w < NWAVES; ++w) acc += sm.red16[w][b][oq * 4 + j];
                s[b][j] = acc * invZ;
                sn += s[b][j] * s[b][j];
            }
            sn += __shfl_xor(sn, 1, 64);
            sn += __shfl_xor(sn, 2, 64);
            float scale = sn / ((1.f + sn) * sqrtf(sn));
#pragma unroll
            for (int j = 0; j < 4; ++j) v[b][j] = s[b][j] * scale;
        }
        if (it < 2) {
#pragma unroll
            for (int b = 0; b < BT; ++b)
#pragma unroll
                for (int k = 0; k < NSTEP; ++k) {
                    const int n = k * 128 + nbase;
                    float2 u0 = unpk(sm.pk[0][b][n][oq]);
                    float2 u1 = unpk(sm.pk[1][b][n][oq]);
                    float d = u0.x * v[b][0] + u0.y * v[b][1] + u1.x * v[b][2] + u1.y * v[b][3];
                    d += __shfl_xor(d, 1, 64);
                    d += __shfl_xor(d, 2, 64);
                    bl[b][k] += d;
                }
        }
    }
    if (tid < 4) {
#pragma unroll
        for (int b = 0; b < BT; ++b) {
            float4 o = make_float4(v[b][0], v[b][1], v[b][2], v[b][3]);
            *reinterpret_cast<float4*>(
                out + ((size_t)(c * BATCH + b0 + b) * COUT) + tid * 4) = o;
        }
    }
}

extern "C" void kernel_launch(void* const* d_in, const int* in_sizes, int n_in,
                              void* d_out, int out_size, void* d_ws, size_t ws_size,
                              hipStream_t stream) {
    const float* x  = (const float*)d_in[0];
    const float* Wt = (const float*)d_in[1];
    float* out = (float*)d_out;
    if (ws_size >= WS_NEEDED) {
        k1_priors<<<dim3(2880), dim3(256), 0, stream>>>(x, Wt, (uint2*)d_ws);
        k2_route<<<dim3(NCAPS * BATCH), dim3(128), 0, stream>>>(
            (const uint4*)d_ws, out);
    } else {
        capsule_routing_kernel<<<dim3(FGRID), dim3(T), 0, stream>>>(x, Wt, out);
    }
}